// Round 3
// baseline (822.046 us; speedup 1.0000x reference)
//
#include <hip/hip_runtime.h>
#include <hip/hip_bf16.h>
#include <math.h>

typedef __hip_bfloat16 bf16;

__device__ __forceinline__ float b2f(bf16 v) { return __bfloat162float(v); }
__device__ __forceinline__ bf16 f2b(float v) { return __float2bfloat16(v); }
__device__ __forceinline__ float us2f(unsigned short u) {
  return __uint_as_float(((unsigned)u) << 16);
}
// dtype-agnostic input load: f32!=0 -> buffer holds fp32, else bf16
__device__ __forceinline__ float ldin(const void* p, size_t i, int f32) {
  return f32 ? ((const float*)p)[i] : b2f(((const bf16*)p)[i]);
}

// Problem constants
#define CC 192
#define DD 8
#define HH 32
#define WW 32
#define NHEAD 6
#define HDIM 32
#define HID 768
#define NTOK 8192
#define ATT_SCALE 0.17677669529663687f  // 32^-0.5

// ---------------------------------------------------------------------------
// Dtype probe: read first 256 halfwords of x as bf16. Genuine bf16 N(0,1)
// data -> all magnitudes in [~1e-4, 6] (insane ~ 0). fp32 data read as
// halfwords -> even halves are mantissa bits with uniform-random exponent
// (insane ~ 115). flag=1 means inputs are fp32.
// ---------------------------------------------------------------------------
__global__ void probe_dtype_kernel(const unsigned short* __restrict__ xu,
                                   int* __restrict__ flag) {
  if (threadIdx.x == 0 && blockIdx.x == 0) {
    int insane = 0;
    for (int i = 0; i < 256; i++) {
      float v = us2f(xu[i]);
      float a = fabsf(v);
      bool sane = (a == 0.0f) || (a > 9.5e-7f && a < 64.0f);
      if (!sane) insane++;
    }
    *flag = (insane > 32) ? 1 : 0;
  }
}

// ---------------------------------------------------------------------------
// t[r, c] = x[c,d,h,w] + pos_emb[d,c];  r = (h*32+w)*8 + d   (fp32 out)
// ---------------------------------------------------------------------------
__global__ void build_t_kernel(const void* __restrict__ x,
                               const void* __restrict__ pos,
                               float* __restrict__ T,
                               const int* __restrict__ dfl) {
  int f32 = *dfl;
  int idx = blockIdx.x * blockDim.x + threadIdx.x;
  if (idx >= NTOK * CC) return;
  int r = idx / CC;
  int c = idx - r * CC;
  int d = r & 7;
  int hw = r >> 3;
  float xv = ldin(x, (size_t)((c << 3) + d) * 1024 + hw, f32);
  float pv = ldin(pos, (size_t)d * CC + c, f32);
  T[idx] = xv + pv;
}

// ---------------------------------------------------------------------------
// LayerNorm over C=192: one 64-lane wave per row; fp32 in, bf16 out
// ---------------------------------------------------------------------------
__global__ void ln_kernel(const float* __restrict__ in, bf16* __restrict__ out,
                          const void* __restrict__ g, const void* __restrict__ b,
                          int rows, const int* __restrict__ dfl) {
  int f32 = *dfl;
  int wave = (blockIdx.x * blockDim.x + threadIdx.x) >> 6;
  int lane = threadIdx.x & 63;
  if (wave >= rows) return;
  const float* r = in + (size_t)wave * CC;
  float v0 = r[lane], v1 = r[lane + 64], v2 = r[lane + 128];
  float s = v0 + v1 + v2;
  for (int off = 32; off; off >>= 1) s += __shfl_xor(s, off);
  float mean = s * (1.0f / CC);
  float d0 = v0 - mean, d1 = v1 - mean, d2 = v2 - mean;
  float q = d0 * d0 + d1 * d1 + d2 * d2;
  for (int off = 32; off; off >>= 1) q += __shfl_xor(q, off);
  float rstd = rsqrtf(q * (1.0f / CC) + 1e-5f);
  bf16* o = out + (size_t)wave * CC;
  o[lane]       = f2b(d0 * rstd * ldin(g, lane, f32)       + ldin(b, lane, f32));
  o[lane + 64]  = f2b(d1 * rstd * ldin(g, lane + 64, f32)  + ldin(b, lane + 64, f32));
  o[lane + 128] = f2b(d2 * rstd * ldin(g, lane + 128, f32) + ldin(b, lane + 128, f32));
}

// ---------------------------------------------------------------------------
// GEMM: out[M,N] = act(A[M,K] @ W[K,N] + bias) (+ residual R fp32)
// A bf16 row-major (workspace), W/bias external (flag dtype).
// 64x64 tile, BK=16, 256 thr, 4x4 per thread. OUTBF: write bf16, else fp32.
// ---------------------------------------------------------------------------
template <bool BIAS, bool GELU, bool RES, bool OUTBF>
__global__ void gemm_kernel(const bf16* __restrict__ A, const void* __restrict__ W,
                            const void* __restrict__ bias, const float* __restrict__ R,
                            void* __restrict__ Cout, int M, int N, int K,
                            const int* __restrict__ dfl) {
  int f32 = *dfl;
  __shared__ float As[16][65];
  __shared__ float Bs[16][65];
  int bm = blockIdx.y * 64, bn = blockIdx.x * 64;
  int tid = threadIdx.x;
  int tm = (tid >> 4) << 2, tn = (tid & 15) << 2;
  float acc[4][4] = {};
  int arow = tid >> 2, aquad = tid & 3;
  const unsigned short* Au = reinterpret_cast<const unsigned short*>(A);
  for (int k0 = 0; k0 < K; k0 += 16) {
    ushort4 av = *reinterpret_cast<const ushort4*>(
        &Au[(size_t)(bm + arow) * K + k0 + aquad * 4]);
    As[aquad * 4 + 0][arow] = us2f(av.x);
    As[aquad * 4 + 1][arow] = us2f(av.y);
    As[aquad * 4 + 2][arow] = us2f(av.z);
    As[aquad * 4 + 3][arow] = us2f(av.w);
#pragma unroll
    for (int e = 0; e < 4; e++) {
      int l = e * 256 + tid;
      int kk = l >> 6, n = l & 63;
      Bs[kk][n] = ldin(W, (size_t)(k0 + kk) * N + bn + n, f32);
    }
    __syncthreads();
#pragma unroll
    for (int kk = 0; kk < 16; kk++) {
      float a0 = As[kk][tm], a1 = As[kk][tm + 1], a2 = As[kk][tm + 2], a3 = As[kk][tm + 3];
      float b0 = Bs[kk][tn], b1 = Bs[kk][tn + 1], b2 = Bs[kk][tn + 2], b3 = Bs[kk][tn + 3];
      acc[0][0] += a0 * b0; acc[0][1] += a0 * b1; acc[0][2] += a0 * b2; acc[0][3] += a0 * b3;
      acc[1][0] += a1 * b0; acc[1][1] += a1 * b1; acc[1][2] += a1 * b2; acc[1][3] += a1 * b3;
      acc[2][0] += a2 * b0; acc[2][1] += a2 * b1; acc[2][2] += a2 * b2; acc[2][3] += a2 * b3;
      acc[3][0] += a3 * b0; acc[3][1] += a3 * b1; acc[3][2] += a3 * b2; acc[3][3] += a3 * b3;
    }
    __syncthreads();
  }
#pragma unroll
  for (int i = 0; i < 4; i++) {
#pragma unroll
    for (int j = 0; j < 4; j++) {
      float v = acc[i][j];
      if (BIAS) v += ldin(bias, bn + tn + j, f32);
      if (GELU) v = 0.5f * v * (1.0f + erff(v * 0.70710678118654752f));
      size_t idx = (size_t)(bm + tm + i) * N + bn + tn + j;
      if (RES) v += R[idx];
      if (OUTBF) ((bf16*)Cout)[idx] = f2b(v);
      else       ((float*)Cout)[idx] = v;
    }
  }
}

// ---------------------------------------------------------------------------
// Time attention: one block per sequence n (1024), 192 threads (6 heads x 32)
// qkv row (n*8+s) bf16 (workspace), cols [3, nh, 32]; O bf16
// ---------------------------------------------------------------------------
__global__ void time_attn_kernel(const bf16* __restrict__ qkv, bf16* __restrict__ O) {
  __shared__ float q[NHEAD][DD][HDIM];
  __shared__ float k[NHEAD][DD][HDIM];
  __shared__ float v[NHEAD][DD][HDIM];
  __shared__ float p[NHEAD][DD][DD];
  int n = blockIdx.x;
  int head = threadIdx.x >> 5;
  int dd = threadIdx.x & 31;
  for (int s = 0; s < DD; s++) {
    const bf16* row = qkv + (size_t)(n * DD + s) * (3 * CC);
    q[head][s][dd] = b2f(row[head * HDIM + dd]);
    k[head][s][dd] = b2f(row[CC + head * HDIM + dd]);
    v[head][s][dd] = b2f(row[2 * CC + head * HDIM + dd]);
  }
  __syncthreads();
  for (int pair = dd; pair < 64; pair += 32) {
    int sq = pair >> 3, sk = pair & 7;
    float sum = 0.f;
#pragma unroll
    for (int e = 0; e < HDIM; e++) sum += q[head][sq][e] * k[head][sk][e];
    p[head][sq][sk] = sum * ATT_SCALE;
  }
  __syncthreads();
  if (dd < DD) {
    float mx = -1e30f;
    for (int sk = 0; sk < DD; sk++) mx = fmaxf(mx, p[head][dd][sk]);
    float sum = 0.f;
    for (int sk = 0; sk < DD; sk++) { float e = expf(p[head][dd][sk] - mx); p[head][dd][sk] = e; sum += e; }
    float inv = 1.0f / sum;
    for (int sk = 0; sk < DD; sk++) p[head][dd][sk] *= inv;
  }
  __syncthreads();
  for (int sq = 0; sq < DD; sq++) {
    float sum = 0.f;
#pragma unroll
    for (int sk = 0; sk < DD; sk++) sum += p[head][sq][sk] * v[head][sk][dd];
    O[(size_t)(n * DD + sq) * CC + head * HDIM + dd] = f2b(sum);
  }
}

// ---------------------------------------------------------------------------
// Time epilogue: lnf over T rows, add original x, store fp32 in space layout
// X1T[m, c] = x[c,d,h,w] + lnf(T)[r,c];  r = hw*8+d, m = d*1024+hw
// ---------------------------------------------------------------------------
__global__ void time_epilogue_kernel(const float* __restrict__ T, const void* __restrict__ x,
                                     const void* __restrict__ g, const void* __restrict__ b,
                                     float* __restrict__ X1T, const int* __restrict__ dfl) {
  int f32 = *dfl;
  int wave = (blockIdx.x * blockDim.x + threadIdx.x) >> 6;
  int lane = threadIdx.x & 63;
  if (wave >= NTOK) return;
  const float* r = T + (size_t)wave * CC;
  float v0 = r[lane], v1 = r[lane + 64], v2 = r[lane + 128];
  float s = v0 + v1 + v2;
  for (int off = 32; off; off >>= 1) s += __shfl_xor(s, off);
  float mean = s * (1.0f / CC);
  float d0 = v0 - mean, d1 = v1 - mean, d2 = v2 - mean;
  float q = d0 * d0 + d1 * d1 + d2 * d2;
  for (int off = 32; off; off >>= 1) q += __shfl_xor(q, off);
  float rstd = rsqrtf(q * (1.0f / CC) + 1e-5f);
  int d = wave & 7, hw = wave >> 3;
  int m = d * 1024 + hw;
  float* o = X1T + (size_t)m * CC;
#pragma unroll
  for (int e = 0; e < 3; e++) {
    int c = lane + e * 64;
    float dv = (e == 0 ? d0 : (e == 1 ? d1 : d2));
    float normed = dv * rstd * ldin(g, c, f32) + ldin(b, c, f32);
    float xv = ldin(x, (size_t)((c << 3) + d) * 1024 + hw, f32);
    o[c] = xv + normed;
  }
}

// ---------------------------------------------------------------------------
// NAT attention: one block per token m (8192), 192 threads (6 heads x 32)
// qkv bf16 (workspace), O bf16, rpb external
// ---------------------------------------------------------------------------
__global__ void nat_attn_kernel(const bf16* __restrict__ qkv, const void* __restrict__ rpb,
                                bf16* __restrict__ O, const int* __restrict__ dfl) {
  int f32 = *dfl;
  __shared__ float sc[NHEAD][49];
  int m = blockIdx.x;
  int d = m >> 10;
  int hw = m & 1023;
  int hy = hw >> 5, wx = hw & 31;
  int head = threadIdx.x >> 5;
  int lane = threadIdx.x & 31;
  int sh = min(max(hy - 3, 0), HH - 7);
  int sw = min(max(wx - 3, 0), WW - 7);
  float qv = b2f(qkv[(size_t)m * (3 * CC) + head * HDIM + lane]) * ATT_SCALE;
  for (int j = 0; j < 49; j++) {
    int a = j / 7, bb = j - a * 7;
    int ih = sh + a, iw = sw + bb;
    int mn = d * 1024 + ih * 32 + iw;
    float kv = b2f(qkv[(size_t)mn * (3 * CC) + CC + head * HDIM + lane]);
    float prod = qv * kv;
    for (int off = 16; off; off >>= 1) prod += __shfl_xor(prod, off, 32);
    if (lane == 0) {
      float bias = ldin(rpb, (size_t)head * 169 + (ih - hy + 6) * 13 + (iw - wx + 6), f32);
      sc[head][j] = prod + bias;
    }
  }
  __syncthreads();
  float mx = -1e30f;
  for (int j = lane; j < 49; j += 32) mx = fmaxf(mx, sc[head][j]);
  for (int off = 16; off; off >>= 1) mx = fmaxf(mx, __shfl_xor(mx, off, 32));
  float sum = 0.f;
  for (int j = lane; j < 49; j += 32) {
    float e = expf(sc[head][j] - mx);
    sc[head][j] = e;
    sum += e;
  }
  for (int off = 16; off; off >>= 1) sum += __shfl_xor(sum, off, 32);
  __syncthreads();
  float inv = 1.0f / sum;
  float acc = 0.f;
  for (int j = 0; j < 49; j++) {
    int a = j / 7, bb = j - a * 7;
    int mn = d * 1024 + (sh + a) * 32 + (sw + bb);
    acc += sc[head][j] * b2f(qkv[(size_t)mn * (3 * CC) + 2 * CC + head * HDIM + lane]);
  }
  O[(size_t)m * CC + head * HDIM + lane] = f2b(acc * inv);
}

// ---------------------------------------------------------------------------
// Final: out[c,d,h,w] = X1T[m,c] + S[m,c], m = d*1024 + h*32 + w
// Output dtype selected by flag.
// ---------------------------------------------------------------------------
__global__ void final_add_kernel(const float* __restrict__ X1T, const float* __restrict__ S,
                                 void* __restrict__ out, const int* __restrict__ dfl) {
  int f32 = *dfl;
  int idx = blockIdx.x * blockDim.x + threadIdx.x;
  if (idx >= CC * NTOK) return;
  int c = idx >> 13;
  int rem = idx & 8191;
  float v = X1T[(size_t)rem * CC + c] + S[(size_t)rem * CC + c];
  if (f32) ((float*)out)[idx] = v;
  else     ((bf16*)out)[idx] = f2b(v);
}

// ---------------------------------------------------------------------------
extern "C" void kernel_launch(void* const* d_in, const int* in_sizes, int n_in,
                              void* d_out, int out_size, void* d_ws, size_t ws_size,
                              hipStream_t stream) {
  const void* x        = d_in[0];
  const void* pos_emb  = d_in[1];
  const void* t_ln1_g  = d_in[2];
  const void* t_ln1_b  = d_in[3];
  const void* t_qkv_w  = d_in[4];
  const void* t_out_w  = d_in[5];
  const void* t_out_b  = d_in[6];
  const void* t_ln2_g  = d_in[7];
  const void* t_ln2_b  = d_in[8];
  const void* t_fc1_w  = d_in[9];
  const void* t_fc1_b  = d_in[10];
  const void* t_fc2_w  = d_in[11];
  const void* t_fc2_b  = d_in[12];
  const void* t_lnf_g  = d_in[13];
  const void* t_lnf_b  = d_in[14];
  const void* s_ln1_g  = d_in[15];
  const void* s_ln1_b  = d_in[16];
  const void* s_qkv_w  = d_in[17];
  const void* s_qkv_b  = d_in[18];
  const void* s_rpb    = d_in[19];
  const void* s_proj_w = d_in[20];
  const void* s_proj_b = d_in[21];
  const void* s_ln2_g  = d_in[22];
  const void* s_ln2_b  = d_in[23];
  const void* s_fc1_w  = d_in[24];
  const void* s_fc1_b  = d_in[25];
  const void* s_fc2_w  = d_in[26];
  const void* s_fc2_b  = d_in[27];

  // Workspace layout (SZ = 8192*192 = 1572864 elements):
  //   [0   , SZ  ) f32 : T / S (residual accumulator)
  //   [SZ  , 2SZ ) f32 : X1T
  //   [2SZ , 2.5SZ) bf16: Y (LN out)
  //   [2.5SZ, 3SZ) bf16: O (attn out)
  //   [3SZ , 5SZ ) bf16: QKV (3SZ bf16) / Hb (4SZ bf16) shared
  //   [5SZ] int  : dtype flag
  float* ws = (float*)d_ws;
  const size_t SZ = (size_t)NTOK * CC;
  const size_t need = (5 * SZ + 4) * sizeof(float);
  if (ws_size < need) return;  // diagnostic: output stays zero (finite absmax)

  float* T   = ws;
  float* X1T = ws + SZ;
  bf16*  Y   = (bf16*)(ws + 2 * SZ);
  bf16*  O   = (bf16*)(ws + 2 * SZ + SZ / 2);
  bf16*  QKV = (bf16*)(ws + 3 * SZ);
  bf16*  Hb  = QKV;
  float* S   = T;
  int*   dfl = (int*)(ws + 5 * SZ);

  const int elems = NTOK * CC;
  dim3 blk256(256);

  probe_dtype_kernel<<<1, 64, 0, stream>>>((const unsigned short*)x, dfl);

  // ---- Time transformer ----
  build_t_kernel<<<(elems + 255) / 256, blk256, 0, stream>>>(x, pos_emb, T, dfl);
  ln_kernel<<<NTOK / 4, blk256, 0, stream>>>(T, Y, t_ln1_g, t_ln1_b, NTOK, dfl);
  gemm_kernel<false, false, false, true><<<dim3(9, 128), blk256, 0, stream>>>(
      Y, t_qkv_w, nullptr, nullptr, QKV, NTOK, 3 * CC, CC, dfl);
  time_attn_kernel<<<1024, 192, 0, stream>>>(QKV, O);
  gemm_kernel<true, false, true, false><<<dim3(3, 128), blk256, 0, stream>>>(
      O, t_out_w, t_out_b, T, T, NTOK, CC, CC, dfl);
  ln_kernel<<<NTOK / 4, blk256, 0, stream>>>(T, Y, t_ln2_g, t_ln2_b, NTOK, dfl);
  gemm_kernel<true, true, false, true><<<dim3(12, 128), blk256, 0, stream>>>(
      Y, t_fc1_w, t_fc1_b, nullptr, Hb, NTOK, HID, CC, dfl);
  gemm_kernel<true, false, true, false><<<dim3(3, 128), blk256, 0, stream>>>(
      Hb, t_fc2_w, t_fc2_b, T, T, NTOK, CC, HID, dfl);
  time_epilogue_kernel<<<NTOK / 4, blk256, 0, stream>>>(T, x, t_lnf_g, t_lnf_b, X1T, dfl);

  // ---- Space transformer ----
  ln_kernel<<<NTOK / 4, blk256, 0, stream>>>(X1T, Y, s_ln1_g, s_ln1_b, NTOK, dfl);
  gemm_kernel<true, false, false, true><<<dim3(9, 128), blk256, 0, stream>>>(
      Y, s_qkv_w, s_qkv_b, nullptr, QKV, NTOK, 3 * CC, CC, dfl);
  nat_attn_kernel<<<NTOK, 192, 0, stream>>>(QKV, s_rpb, O, dfl);
  gemm_kernel<true, false, true, false><<<dim3(3, 128), blk256, 0, stream>>>(
      O, s_proj_w, s_proj_b, X1T, S, NTOK, CC, CC, dfl);
  ln_kernel<<<NTOK / 4, blk256, 0, stream>>>(S, Y, s_ln2_g, s_ln2_b, NTOK, dfl);
  gemm_kernel<true, true, false, true><<<dim3(12, 128), blk256, 0, stream>>>(
      Y, s_fc1_w, s_fc1_b, nullptr, Hb, NTOK, HID, CC, dfl);
  gemm_kernel<true, false, true, false><<<dim3(3, 128), blk256, 0, stream>>>(
      Hb, s_fc2_w, s_fc2_b, S, S, NTOK, CC, HID, dfl);

  // ---- Output ----
  final_add_kernel<<<(elems + 255) / 256, blk256, 0, stream>>>(X1T, S, out_size ? d_out : d_out, dfl);
}

// Round 4
// 366.304 us; speedup vs baseline: 2.2442x; 2.2442x over previous
//
#include <hip/hip_runtime.h>
#include <hip/hip_bf16.h>
#include <math.h>

typedef __hip_bfloat16 bf16;
typedef short bf16x8 __attribute__((ext_vector_type(8)));
typedef float f32x4 __attribute__((ext_vector_type(4)));

__device__ __forceinline__ float b2f(bf16 v) { return __bfloat162float(v); }
__device__ __forceinline__ bf16 f2b(float v) { return __float2bfloat16(v); }
__device__ __forceinline__ float us2f(unsigned short u) {
  return __uint_as_float(((unsigned)u) << 16);
}
__device__ __forceinline__ unsigned short f2us(float f) {
  bf16 h = __float2bfloat16(f);
  return *reinterpret_cast<unsigned short*>(&h);
}
// dtype-agnostic input load: f32!=0 -> buffer holds fp32, else bf16
__device__ __forceinline__ float ldin(const void* p, size_t i, int f32) {
  return f32 ? ((const float*)p)[i] : b2f(((const bf16*)p)[i]);
}

// Problem constants
#define CC 192
#define DD 8
#define HH 32
#define WW 32
#define NHEAD 6
#define HDIM 32
#define HID 768
#define NTOK 8192
#define ATT_SCALE 0.17677669529663687f  // 32^-0.5

// ---------------------------------------------------------------------------
// Dtype probe (unchanged, proven): flag=1 means inputs are fp32.
// ---------------------------------------------------------------------------
__global__ void probe_dtype_kernel(const unsigned short* __restrict__ xu,
                                   int* __restrict__ flag) {
  if (threadIdx.x == 0 && blockIdx.x == 0) {
    int insane = 0;
    for (int i = 0; i < 256; i++) {
      float v = us2f(xu[i]);
      float a = fabsf(v);
      bool sane = (a == 0.0f) || (a > 9.5e-7f && a < 64.0f);
      if (!sane) insane++;
    }
    *flag = (insane > 32) ? 1 : 0;
  }
}

// ---------------------------------------------------------------------------
// t[r, c] = x[c,d,h,w] + pos_emb[d,c];  r = (h*32+w)*8 + d   (fp32 out)
// ---------------------------------------------------------------------------
__global__ void build_t_kernel(const void* __restrict__ x,
                               const void* __restrict__ pos,
                               float* __restrict__ T,
                               const int* __restrict__ dfl) {
  int f32 = *dfl;
  int idx = blockIdx.x * blockDim.x + threadIdx.x;
  if (idx >= NTOK * CC) return;
  int r = idx / CC;
  int c = idx - r * CC;
  int d = r & 7;
  int hw = r >> 3;
  float xv = ldin(x, (size_t)((c << 3) + d) * 1024 + hw, f32);
  float pv = ldin(pos, (size_t)d * CC + c, f32);
  T[idx] = xv + pv;
}

// ---------------------------------------------------------------------------
// LayerNorm over C=192: one 64-lane wave per row; fp32 in, bf16 out
// ---------------------------------------------------------------------------
__global__ void ln_kernel(const float* __restrict__ in, bf16* __restrict__ out,
                          const void* __restrict__ g, const void* __restrict__ b,
                          int rows, const int* __restrict__ dfl) {
  int f32 = *dfl;
  int wave = (blockIdx.x * blockDim.x + threadIdx.x) >> 6;
  int lane = threadIdx.x & 63;
  if (wave >= rows) return;
  const float* r = in + (size_t)wave * CC;
  float v0 = r[lane], v1 = r[lane + 64], v2 = r[lane + 128];
  float s = v0 + v1 + v2;
  for (int off = 32; off; off >>= 1) s += __shfl_xor(s, off);
  float mean = s * (1.0f / CC);
  float d0 = v0 - mean, d1 = v1 - mean, d2 = v2 - mean;
  float q = d0 * d0 + d1 * d1 + d2 * d2;
  for (int off = 32; off; off >>= 1) q += __shfl_xor(q, off);
  float rstd = rsqrtf(q * (1.0f / CC) + 1e-5f);
  bf16* o = out + (size_t)wave * CC;
  o[lane]       = f2b(d0 * rstd * ldin(g, lane, f32)       + ldin(b, lane, f32));
  o[lane + 64]  = f2b(d1 * rstd * ldin(g, lane + 64, f32)  + ldin(b, lane + 64, f32));
  o[lane + 128] = f2b(d2 * rstd * ldin(g, lane + 128, f32) + ldin(b, lane + 128, f32));
}

// ---------------------------------------------------------------------------
// MFMA GEMM: out[M,N] = act(A[M,K] @ W[K,N] + bias) (+ residual R fp32)
// A bf16 row-major (workspace). W/bias external (flag dtype), W converted to
// bf16 at LDS stage. Block tile 128Mx64N, BK=32, 256 threads = 4 waves,
// each wave computes 32x64 via 2x4 grid of 16x16x32 bf16 MFMAs.
// LDS rows padded to 40 elems (80 B) for 16B-aligned ds_read_b128.
// ---------------------------------------------------------------------------
template <bool BIAS, bool GELU, bool RES, bool OUTBF>
__global__ void gemm_kernel(const bf16* __restrict__ A, const void* __restrict__ W,
                            const void* __restrict__ bias, const float* __restrict__ R,
                            void* __restrict__ Cout, int M, int N, int K,
                            const int* __restrict__ dfl) {
  int f32 = *dfl;
  __shared__ __align__(16) unsigned short As[128 * 40];
  __shared__ __align__(16) unsigned short Bs[64 * 40];
  int bm = blockIdx.y * 128, bn = blockIdx.x * 64;
  int tid = threadIdx.x;
  int w = tid >> 6;        // wave id 0..3: rows [w*32, w*32+32)
  int lane = tid & 63;
  int lm = lane & 15;      // fragment row/col
  int lk = lane >> 4;      // fragment k-group

  f32x4 acc[2][4];
#pragma unroll
  for (int i = 0; i < 2; i++)
#pragma unroll
    for (int j = 0; j < 4; j++) acc[i][j] = (f32x4){0.f, 0.f, 0.f, 0.f};

  const unsigned short* Au = reinterpret_cast<const unsigned short*>(A);

  for (int k0 = 0; k0 < K; k0 += 32) {
    // --- stage A tile: 128 rows x 32 k (two 16B units per thread) ---
#pragma unroll
    for (int u = 0; u < 2; u++) {
      int unit = tid + u * 256;           // 0..511
      int row = unit >> 2, seg = unit & 3;
      uint4 v = *reinterpret_cast<const uint4*>(
          &Au[(size_t)(bm + row) * K + k0 + seg * 8]);
      *reinterpret_cast<uint4*>(&As[row * 40 + seg * 8]) = v;
    }
    // --- stage W tile transposed: Bs[n][k], 32k x 64n, 8 elems/thread ---
    {
      int e0 = tid * 8;
      int kk = e0 >> 6, n0 = e0 & 63;
      unsigned short vals[8];
      if (f32) {
        const float* Wf = (const float*)W + (size_t)(k0 + kk) * N + bn + n0;
        float4 w0 = *reinterpret_cast<const float4*>(Wf);
        float4 w1 = *reinterpret_cast<const float4*>(Wf + 4);
        vals[0] = f2us(w0.x); vals[1] = f2us(w0.y); vals[2] = f2us(w0.z); vals[3] = f2us(w0.w);
        vals[4] = f2us(w1.x); vals[5] = f2us(w1.y); vals[6] = f2us(w1.z); vals[7] = f2us(w1.w);
      } else {
        const unsigned short* Wb = (const unsigned short*)W + (size_t)(k0 + kk) * N + bn + n0;
        ushort4 u0 = *reinterpret_cast<const ushort4*>(Wb);
        ushort4 u1 = *reinterpret_cast<const ushort4*>(Wb + 4);
        vals[0] = u0.x; vals[1] = u0.y; vals[2] = u0.z; vals[3] = u0.w;
        vals[4] = u1.x; vals[5] = u1.y; vals[6] = u1.z; vals[7] = u1.w;
      }
#pragma unroll
      for (int j = 0; j < 8; j++) Bs[(n0 + j) * 40 + kk] = vals[j];
    }
    __syncthreads();

    // --- MFMA: 2 A-frags, 4 B-frags, 8 mfma ---
    bf16x8 af[2], bf[4];
#pragma unroll
    for (int tm = 0; tm < 2; tm++)
      af[tm] = *reinterpret_cast<const bf16x8*>(
          &As[(w * 32 + tm * 16 + lm) * 40 + lk * 8]);
#pragma unroll
    for (int tn = 0; tn < 4; tn++)
      bf[tn] = *reinterpret_cast<const bf16x8*>(
          &Bs[(tn * 16 + lm) * 40 + lk * 8]);
#pragma unroll
    for (int tm = 0; tm < 2; tm++)
#pragma unroll
      for (int tn = 0; tn < 4; tn++)
        acc[tm][tn] = __builtin_amdgcn_mfma_f32_16x16x32_bf16(
            af[tm], bf[tn], acc[tm][tn], 0, 0, 0);
    __syncthreads();
  }

  // --- epilogue ---
#pragma unroll
  for (int tn = 0; tn < 4; tn++) {
    int col = bn + tn * 16 + lm;
    float bv = BIAS ? ldin(bias, col, f32) : 0.f;
#pragma unroll
    for (int tm = 0; tm < 2; tm++) {
      int row0 = bm + w * 32 + tm * 16 + lk * 4;
#pragma unroll
      for (int r = 0; r < 4; r++) {
        float v = acc[tm][tn][r];
        if (BIAS) v += bv;
        if (GELU) v = 0.5f * v * (1.0f + erff(v * 0.70710678118654752f));
        size_t idx = (size_t)(row0 + r) * N + col;
        if (RES) v += R[idx];
        if (OUTBF) ((bf16*)Cout)[idx] = f2b(v);
        else       ((float*)Cout)[idx] = v;
      }
    }
  }
}

// ---------------------------------------------------------------------------
// Time attention (unchanged): one block per sequence n (1024), 192 threads
// ---------------------------------------------------------------------------
__global__ void time_attn_kernel(const bf16* __restrict__ qkv, bf16* __restrict__ O) {
  __shared__ float q[NHEAD][DD][HDIM];
  __shared__ float k[NHEAD][DD][HDIM];
  __shared__ float v[NHEAD][DD][HDIM];
  __shared__ float p[NHEAD][DD][DD];
  int n = blockIdx.x;
  int head = threadIdx.x >> 5;
  int dd = threadIdx.x & 31;
  for (int s = 0; s < DD; s++) {
    const bf16* row = qkv + (size_t)(n * DD + s) * (3 * CC);
    q[head][s][dd] = b2f(row[head * HDIM + dd]);
    k[head][s][dd] = b2f(row[CC + head * HDIM + dd]);
    v[head][s][dd] = b2f(row[2 * CC + head * HDIM + dd]);
  }
  __syncthreads();
  for (int pair = dd; pair < 64; pair += 32) {
    int sq = pair >> 3, sk = pair & 7;
    float sum = 0.f;
#pragma unroll
    for (int e = 0; e < HDIM; e++) sum += q[head][sq][e] * k[head][sk][e];
    p[head][sq][sk] = sum * ATT_SCALE;
  }
  __syncthreads();
  if (dd < DD) {
    float mx = -1e30f;
    for (int sk = 0; sk < DD; sk++) mx = fmaxf(mx, p[head][dd][sk]);
    float sum = 0.f;
    for (int sk = 0; sk < DD; sk++) { float e = expf(p[head][dd][sk] - mx); p[head][dd][sk] = e; sum += e; }
    float inv = 1.0f / sum;
    for (int sk = 0; sk < DD; sk++) p[head][dd][sk] *= inv;
  }
  __syncthreads();
  for (int sq = 0; sq < DD; sq++) {
    float sum = 0.f;
#pragma unroll
    for (int sk = 0; sk < DD; sk++) sum += p[head][sq][sk] * v[head][sk][dd];
    O[(size_t)(n * DD + sq) * CC + head * HDIM + dd] = f2b(sum);
  }
}

// ---------------------------------------------------------------------------
// Time epilogue (unchanged)
// ---------------------------------------------------------------------------
__global__ void time_epilogue_kernel(const float* __restrict__ T, const void* __restrict__ x,
                                     const void* __restrict__ g, const void* __restrict__ b,
                                     float* __restrict__ X1T, const int* __restrict__ dfl) {
  int f32 = *dfl;
  int wave = (blockIdx.x * blockDim.x + threadIdx.x) >> 6;
  int lane = threadIdx.x & 63;
  if (wave >= NTOK) return;
  const float* r = T + (size_t)wave * CC;
  float v0 = r[lane], v1 = r[lane + 64], v2 = r[lane + 128];
  float s = v0 + v1 + v2;
  for (int off = 32; off; off >>= 1) s += __shfl_xor(s, off);
  float mean = s * (1.0f / CC);
  float d0 = v0 - mean, d1 = v1 - mean, d2 = v2 - mean;
  float q = d0 * d0 + d1 * d1 + d2 * d2;
  for (int off = 32; off; off >>= 1) q += __shfl_xor(q, off);
  float rstd = rsqrtf(q * (1.0f / CC) + 1e-5f);
  int d = wave & 7, hw = wave >> 3;
  int m = d * 1024 + hw;
  float* o = X1T + (size_t)m * CC;
#pragma unroll
  for (int e = 0; e < 3; e++) {
    int c = lane + e * 64;
    float dv = (e == 0 ? d0 : (e == 1 ? d1 : d2));
    float normed = dv * rstd * ldin(g, c, f32) + ldin(b, c, f32);
    float xv = ldin(x, (size_t)((c << 3) + d) * 1024 + hw, f32);
    o[c] = xv + normed;
  }
}

// ---------------------------------------------------------------------------
// NAT attention v2: one block per token m, 192 threads = 6 heads x 32 lanes.
// Score phase: lane j computes a full 32-MAC dot (no cross-lane chains).
// Softmax: one 5-shuffle reduction over LDS scores. V phase: lane = d index.
// ---------------------------------------------------------------------------
__global__ void nat_attn_kernel(const bf16* __restrict__ qkv, const void* __restrict__ rpb,
                                bf16* __restrict__ O, const int* __restrict__ dfl) {
  int f32 = *dfl;
  __shared__ float qs[NHEAD][HDIM];
  __shared__ float sc[NHEAD][52];
  int m = blockIdx.x;
  int d = m >> 10;
  int hw = m & 1023;
  int hy = hw >> 5, wx = hw & 31;
  int h = threadIdx.x >> 5;
  int l = threadIdx.x & 31;
  int sh = min(max(hy - 3, 0), HH - 7);
  int sw = min(max(wx - 3, 0), WW - 7);

  qs[h][l] = b2f(qkv[(size_t)m * (3 * CC) + h * HDIM + l]) * ATT_SCALE;
  __syncthreads();

  // scores: lane j (and j+32) does a full dot against K row j
  for (int j = l; j < 49; j += 32) {
    int a = j / 7, bb = j - a * 7;
    int ih = sh + a, iw = sw + bb;
    int mn = d * 1024 + ih * 32 + iw;
    const uint4* kru = reinterpret_cast<const uint4*>(
        qkv + (size_t)mn * (3 * CC) + CC + h * HDIM);
    float sum = 0.f;
#pragma unroll
    for (int c4 = 0; c4 < 4; c4++) {
      uint4 u = kru[c4];
      unsigned arr[4] = {u.x, u.y, u.z, u.w};
#pragma unroll
      for (int q2 = 0; q2 < 4; q2++) {
        unsigned uu = arr[q2];
        int dd = c4 * 8 + q2 * 2;
        sum += qs[h][dd]     * us2f((unsigned short)(uu & 0xffffu));
        sum += qs[h][dd + 1] * us2f((unsigned short)(uu >> 16));
      }
    }
    float bias = ldin(rpb, (size_t)h * 169 + (ih - hy + 6) * 13 + (iw - wx + 6), f32);
    sc[h][j] = sum + bias;
  }
  __syncthreads();

  // softmax over 49 (within 32-lane head group)
  float mx = -1e30f;
  for (int j = l; j < 49; j += 32) mx = fmaxf(mx, sc[h][j]);
  for (int off = 16; off; off >>= 1) mx = fmaxf(mx, __shfl_xor(mx, off, 32));
  float sum = 0.f;
  float e0 = 0.f, e1 = 0.f;
  {
    e0 = expf(sc[h][l] - mx);
    sum = e0;
    if (l < 17) { e1 = expf(sc[h][l + 32] - mx); sum += e1; }
  }
  for (int off = 16; off; off >>= 1) sum += __shfl_xor(sum, off, 32);
  float inv = 1.0f / sum;
  sc[h][l] = e0 * inv;
  if (l < 17) sc[h][l + 32] = e1 * inv;
  __syncthreads();

  // V phase: lane = d index, accumulate over 49 neighbors
  float acc = 0.f;
  for (int j = 0; j < 49; j++) {
    int a = j / 7, bb = j - a * 7;
    int mn = d * 1024 + (sh + a) * 32 + (sw + bb);
    acc += sc[h][j] * b2f(qkv[(size_t)mn * (3 * CC) + 2 * CC + h * HDIM + l]);
  }
  O[(size_t)m * CC + h * HDIM + l] = f2b(acc);
}

// ---------------------------------------------------------------------------
// Final: out[c,d,h,w] = X1T[m,c] + S[m,c]; dtype by flag
// ---------------------------------------------------------------------------
__global__ void final_add_kernel(const float* __restrict__ X1T, const float* __restrict__ S,
                                 void* __restrict__ out, const int* __restrict__ dfl) {
  int f32 = *dfl;
  int idx = blockIdx.x * blockDim.x + threadIdx.x;
  if (idx >= CC * NTOK) return;
  int c = idx >> 13;
  int rem = idx & 8191;
  float v = X1T[(size_t)rem * CC + c] + S[(size_t)rem * CC + c];
  if (f32) ((float*)out)[idx] = v;
  else     ((bf16*)out)[idx] = f2b(v);
}

// ---------------------------------------------------------------------------
extern "C" void kernel_launch(void* const* d_in, const int* in_sizes, int n_in,
                              void* d_out, int out_size, void* d_ws, size_t ws_size,
                              hipStream_t stream) {
  const void* x        = d_in[0];
  const void* pos_emb  = d_in[1];
  const void* t_ln1_g  = d_in[2];
  const void* t_ln1_b  = d_in[3];
  const void* t_qkv_w  = d_in[4];
  const void* t_out_w  = d_in[5];
  const void* t_out_b  = d_in[6];
  const void* t_ln2_g  = d_in[7];
  const void* t_ln2_b  = d_in[8];
  const void* t_fc1_w  = d_in[9];
  const void* t_fc1_b  = d_in[10];
  const void* t_fc2_w  = d_in[11];
  const void* t_fc2_b  = d_in[12];
  const void* t_lnf_g  = d_in[13];
  const void* t_lnf_b  = d_in[14];
  const void* s_ln1_g  = d_in[15];
  const void* s_ln1_b  = d_in[16];
  const void* s_qkv_w  = d_in[17];
  const void* s_qkv_b  = d_in[18];
  const void* s_rpb    = d_in[19];
  const void* s_proj_w = d_in[20];
  const void* s_proj_b = d_in[21];
  const void* s_ln2_g  = d_in[22];
  const void* s_ln2_b  = d_in[23];
  const void* s_fc1_w  = d_in[24];
  const void* s_fc1_b  = d_in[25];
  const void* s_fc2_w  = d_in[26];
  const void* s_fc2_b  = d_in[27];

  // Workspace (SZ = 8192*192):
  //   [0,SZ) f32 T/S | [SZ,2SZ) f32 X1T | [2SZ,2.5SZ) bf16 Y | [2.5SZ,3SZ) bf16 O
  //   [3SZ,5SZ) bf16 QKV/Hb | [5SZ] int dtype flag.  Total ~31.5 MB.
  float* ws = (float*)d_ws;
  const size_t SZ = (size_t)NTOK * CC;
  const size_t need = (5 * SZ + 4) * sizeof(float);
  if (ws_size < need) return;

  float* T   = ws;
  float* X1T = ws + SZ;
  bf16*  Y   = (bf16*)(ws + 2 * SZ);
  bf16*  O   = (bf16*)(ws + 2 * SZ + SZ / 2);
  bf16*  QKV = (bf16*)(ws + 3 * SZ);
  bf16*  Hb  = QKV;
  float* S   = T;
  int*   dfl = (int*)(ws + 5 * SZ);

  const int elems = NTOK * CC;
  dim3 blk256(256);

  probe_dtype_kernel<<<1, 64, 0, stream>>>((const unsigned short*)x, dfl);

  // ---- Time transformer ----
  build_t_kernel<<<(elems + 255) / 256, blk256, 0, stream>>>(x, pos_emb, T, dfl);
  ln_kernel<<<NTOK / 4, blk256, 0, stream>>>(T, Y, t_ln1_g, t_ln1_b, NTOK, dfl);
  gemm_kernel<false, false, false, true><<<dim3(9, 64), blk256, 0, stream>>>(
      Y, t_qkv_w, nullptr, nullptr, QKV, NTOK, 3 * CC, CC, dfl);
  time_attn_kernel<<<1024, 192, 0, stream>>>(QKV, O);
  gemm_kernel<true, false, true, false><<<dim3(3, 64), blk256, 0, stream>>>(
      O, t_out_w, t_out_b, T, T, NTOK, CC, CC, dfl);
  ln_kernel<<<NTOK / 4, blk256, 0, stream>>>(T, Y, t_ln2_g, t_ln2_b, NTOK, dfl);
  gemm_kernel<true, true, false, true><<<dim3(12, 64), blk256, 0, stream>>>(
      Y, t_fc1_w, t_fc1_b, nullptr, Hb, NTOK, HID, CC, dfl);
  gemm_kernel<true, false, true, false><<<dim3(3, 64), blk256, 0, stream>>>(
      Hb, t_fc2_w, t_fc2_b, T, T, NTOK, CC, HID, dfl);
  time_epilogue_kernel<<<NTOK / 4, blk256, 0, stream>>>(T, x, t_lnf_g, t_lnf_b, X1T, dfl);

  // ---- Space transformer ----
  ln_kernel<<<NTOK / 4, blk256, 0, stream>>>(X1T, Y, s_ln1_g, s_ln1_b, NTOK, dfl);
  gemm_kernel<true, false, false, true><<<dim3(9, 64), blk256, 0, stream>>>(
      Y, s_qkv_w, s_qkv_b, nullptr, QKV, NTOK, 3 * CC, CC, dfl);
  nat_attn_kernel<<<NTOK, 192, 0, stream>>>(QKV, s_rpb, O, dfl);
  gemm_kernel<true, false, true, false><<<dim3(3, 64), blk256, 0, stream>>>(
      O, s_proj_w, s_proj_b, X1T, S, NTOK, CC, CC, dfl);
  ln_kernel<<<NTOK / 4, blk256, 0, stream>>>(S, Y, s_ln2_g, s_ln2_b, NTOK, dfl);
  gemm_kernel<true, true, false, true><<<dim3(12, 64), blk256, 0, stream>>>(
      Y, s_fc1_w, s_fc1_b, nullptr, Hb, NTOK, HID, CC, dfl);
  gemm_kernel<true, false, true, false><<<dim3(3, 64), blk256, 0, stream>>>(
      Hb, s_fc2_w, s_fc2_b, S, S, NTOK, CC, HID, dfl);

  // ---- Output ----
  final_add_kernel<<<(elems + 255) / 256, blk256, 0, stream>>>(X1T, S, d_out, dfl);
}

// Round 5
// 345.700 us; speedup vs baseline: 2.3779x; 1.0596x over previous
//
#include <hip/hip_runtime.h>
#include <hip/hip_bf16.h>
#include <math.h>

typedef __hip_bfloat16 bf16;
typedef short bf16x8 __attribute__((ext_vector_type(8)));
typedef float f32x4 __attribute__((ext_vector_type(4)));

__device__ __forceinline__ float b2f(bf16 v) { return __bfloat162float(v); }
__device__ __forceinline__ bf16 f2b(float v) { return __float2bfloat16(v); }
__device__ __forceinline__ float us2f(unsigned short u) {
  return __uint_as_float(((unsigned)u) << 16);
}
__device__ __forceinline__ unsigned short f2us(float f) {
  bf16 h = __float2bfloat16(f);
  return *reinterpret_cast<unsigned short*>(&h);
}
// dtype-agnostic input load: f32!=0 -> buffer holds fp32, else bf16
__device__ __forceinline__ float ldin(const void* p, size_t i, int f32) {
  return f32 ? ((const float*)p)[i] : b2f(((const bf16*)p)[i]);
}

// Problem constants
#define CC 192
#define DD 8
#define HH 32
#define WW 32
#define NHEAD 6
#define HDIM 32
#define HID 768
#define NTOK 8192
#define ATT_SCALE 0.17677669529663687f  // 32^-0.5

// ---------------------------------------------------------------------------
// Dtype probe (proven): flag=1 means inputs are fp32.
// ---------------------------------------------------------------------------
__global__ void probe_dtype_kernel(const unsigned short* __restrict__ xu,
                                   int* __restrict__ flag) {
  if (threadIdx.x == 0 && blockIdx.x == 0) {
    int insane = 0;
    for (int i = 0; i < 256; i++) {
      float v = us2f(xu[i]);
      float a = fabsf(v);
      bool sane = (a == 0.0f) || (a > 9.5e-7f && a < 64.0f);
      if (!sane) insane++;
    }
    *flag = (insane > 32) ? 1 : 0;
  }
}

// ---------------------------------------------------------------------------
// Fused: T[r,c] = x[c,d,h,w] + pos[d,c];  Y = LN(T)*g+b   (wave per row)
// r = hw*8 + d
// ---------------------------------------------------------------------------
__global__ void build_ln1_kernel(const void* __restrict__ x, const void* __restrict__ pos,
                                 const void* __restrict__ g, const void* __restrict__ b,
                                 float* __restrict__ T, bf16* __restrict__ Y,
                                 const int* __restrict__ dfl) {
  int f32 = *dfl;
  int wave = (blockIdx.x * blockDim.x + threadIdx.x) >> 6;
  int lane = threadIdx.x & 63;
  if (wave >= NTOK) return;
  int d = wave & 7, hw = wave >> 3;
  float v[3];
#pragma unroll
  for (int e = 0; e < 3; e++) {
    int c = lane + e * 64;
    v[e] = ldin(x, (size_t)((c << 3) + d) * 1024 + hw, f32) +
           ldin(pos, (size_t)d * CC + c, f32);
  }
  float* tr = T + (size_t)wave * CC;
#pragma unroll
  for (int e = 0; e < 3; e++) tr[lane + e * 64] = v[e];
  float s = v[0] + v[1] + v[2];
  for (int off = 32; off; off >>= 1) s += __shfl_xor(s, off);
  float mean = s * (1.0f / CC);
  float d0 = v[0] - mean, d1 = v[1] - mean, d2 = v[2] - mean;
  float q = d0 * d0 + d1 * d1 + d2 * d2;
  for (int off = 32; off; off >>= 1) q += __shfl_xor(q, off);
  float rstd = rsqrtf(q * (1.0f / CC) + 1e-5f);
  bf16* o = Y + (size_t)wave * CC;
  o[lane]       = f2b(d0 * rstd * ldin(g, lane, f32)       + ldin(b, lane, f32));
  o[lane + 64]  = f2b(d1 * rstd * ldin(g, lane + 64, f32)  + ldin(b, lane + 64, f32));
  o[lane + 128] = f2b(d2 * rstd * ldin(g, lane + 128, f32) + ldin(b, lane + 128, f32));
}

// ---------------------------------------------------------------------------
// LayerNorm (standalone): fp32 in, bf16 out
// ---------------------------------------------------------------------------
__global__ void ln_kernel(const float* __restrict__ in, bf16* __restrict__ out,
                          const void* __restrict__ g, const void* __restrict__ b,
                          int rows, const int* __restrict__ dfl) {
  int f32 = *dfl;
  int wave = (blockIdx.x * blockDim.x + threadIdx.x) >> 6;
  int lane = threadIdx.x & 63;
  if (wave >= rows) return;
  const float* r = in + (size_t)wave * CC;
  float v0 = r[lane], v1 = r[lane + 64], v2 = r[lane + 128];
  float s = v0 + v1 + v2;
  for (int off = 32; off; off >>= 1) s += __shfl_xor(s, off);
  float mean = s * (1.0f / CC);
  float d0 = v0 - mean, d1 = v1 - mean, d2 = v2 - mean;
  float q = d0 * d0 + d1 * d1 + d2 * d2;
  for (int off = 32; off; off >>= 1) q += __shfl_xor(q, off);
  float rstd = rsqrtf(q * (1.0f / CC) + 1e-5f);
  bf16* o = out + (size_t)wave * CC;
  o[lane]       = f2b(d0 * rstd * ldin(g, lane, f32)       + ldin(b, lane, f32));
  o[lane + 64]  = f2b(d1 * rstd * ldin(g, lane + 64, f32)  + ldin(b, lane + 64, f32));
  o[lane + 128] = f2b(d2 * rstd * ldin(g, lane + 128, f32) + ldin(b, lane + 128, f32));
}

// ---------------------------------------------------------------------------
// MFMA GEMM: out = act(A[M,K] @ W[K,N] + bias) (+ R)  [+ FINAL: transposed out]
// Block tile 128Mx64N, BK=32, 4 waves, each 32x64 via 2x4 of 16x16x32 bf16.
// FINAL: writes dst[col*NTOK + row] = v + X2[row*CC+col]  (dtype by flag)
// ---------------------------------------------------------------------------
template <bool BIAS, bool GELU, bool RES, bool OUTBF, bool FINAL>
__global__ void gemm_kernel(const bf16* __restrict__ A, const void* __restrict__ W,
                            const void* __restrict__ bias, const float* __restrict__ R,
                            void* __restrict__ Cout, const float* __restrict__ X2,
                            int M, int N, int K, const int* __restrict__ dfl) {
  int f32 = *dfl;
  __shared__ __align__(16) unsigned short As[128 * 40];
  __shared__ __align__(16) unsigned short Bs[64 * 40];
  int bm = blockIdx.y * 128, bn = blockIdx.x * 64;
  int tid = threadIdx.x;
  int w = tid >> 6;
  int lane = tid & 63;
  int lm = lane & 15;
  int lk = lane >> 4;

  f32x4 acc[2][4];
#pragma unroll
  for (int i = 0; i < 2; i++)
#pragma unroll
    for (int j = 0; j < 4; j++) acc[i][j] = (f32x4){0.f, 0.f, 0.f, 0.f};

  const unsigned short* Au = reinterpret_cast<const unsigned short*>(A);

  for (int k0 = 0; k0 < K; k0 += 32) {
#pragma unroll
    for (int u = 0; u < 2; u++) {
      int unit = tid + u * 256;
      int row = unit >> 2, seg = unit & 3;
      uint4 v = *reinterpret_cast<const uint4*>(
          &Au[(size_t)(bm + row) * K + k0 + seg * 8]);
      *reinterpret_cast<uint4*>(&As[row * 40 + seg * 8]) = v;
    }
    {
      int e0 = tid * 8;
      int kk = e0 >> 6, n0 = e0 & 63;
      unsigned short vals[8];
      if (f32) {
        const float* Wf = (const float*)W + (size_t)(k0 + kk) * N + bn + n0;
        float4 w0 = *reinterpret_cast<const float4*>(Wf);
        float4 w1 = *reinterpret_cast<const float4*>(Wf + 4);
        vals[0] = f2us(w0.x); vals[1] = f2us(w0.y); vals[2] = f2us(w0.z); vals[3] = f2us(w0.w);
        vals[4] = f2us(w1.x); vals[5] = f2us(w1.y); vals[6] = f2us(w1.z); vals[7] = f2us(w1.w);
      } else {
        const unsigned short* Wb = (const unsigned short*)W + (size_t)(k0 + kk) * N + bn + n0;
        ushort4 u0 = *reinterpret_cast<const ushort4*>(Wb);
        ushort4 u1 = *reinterpret_cast<const ushort4*>(Wb + 4);
        vals[0] = u0.x; vals[1] = u0.y; vals[2] = u0.z; vals[3] = u0.w;
        vals[4] = u1.x; vals[5] = u1.y; vals[6] = u1.z; vals[7] = u1.w;
      }
#pragma unroll
      for (int j = 0; j < 8; j++) Bs[(n0 + j) * 40 + kk] = vals[j];
    }
    __syncthreads();

    bf16x8 af[2], bfr[4];
#pragma unroll
    for (int tm = 0; tm < 2; tm++)
      af[tm] = *reinterpret_cast<const bf16x8*>(
          &As[(w * 32 + tm * 16 + lm) * 40 + lk * 8]);
#pragma unroll
    for (int tn = 0; tn < 4; tn++)
      bfr[tn] = *reinterpret_cast<const bf16x8*>(
          &Bs[(tn * 16 + lm) * 40 + lk * 8]);
#pragma unroll
    for (int tm = 0; tm < 2; tm++)
#pragma unroll
      for (int tn = 0; tn < 4; tn++)
        acc[tm][tn] = __builtin_amdgcn_mfma_f32_16x16x32_bf16(
            af[tm], bfr[tn], acc[tm][tn], 0, 0, 0);
    __syncthreads();
  }

#pragma unroll
  for (int tn = 0; tn < 4; tn++) {
    int col = bn + tn * 16 + lm;
    float bv = BIAS ? ldin(bias, col, f32) : 0.f;
#pragma unroll
    for (int tm = 0; tm < 2; tm++) {
      int row0 = bm + w * 32 + tm * 16 + lk * 4;
#pragma unroll
      for (int r = 0; r < 4; r++) {
        int row = row0 + r;
        float v = acc[tm][tn][r];
        if (BIAS) v += bv;
        if (GELU) v = 0.5f * v * (1.0f + erff(v * 0.70710678118654752f));
        size_t idx = (size_t)row * N + col;
        if (RES) v += R[idx];
        if (FINAL) {
          float o = v + X2[(size_t)row * CC + col];
          if (f32) ((float*)Cout)[(size_t)col * NTOK + row] = o;
          else     ((bf16*)Cout)[(size_t)col * NTOK + row] = f2b(o);
        } else if (OUTBF) {
          ((bf16*)Cout)[idx] = f2b(v);
        } else {
          ((float*)Cout)[idx] = v;
        }
      }
    }
  }
}

// ---------------------------------------------------------------------------
// Time attention: one block per sequence n (1024), 192 threads
// ---------------------------------------------------------------------------
__global__ void time_attn_kernel(const bf16* __restrict__ qkv, bf16* __restrict__ O) {
  __shared__ float q[NHEAD][DD][HDIM];
  __shared__ float k[NHEAD][DD][HDIM];
  __shared__ float v[NHEAD][DD][HDIM];
  __shared__ float p[NHEAD][DD][DD];
  int n = blockIdx.x;
  int head = threadIdx.x >> 5;
  int dd = threadIdx.x & 31;
  for (int s = 0; s < DD; s++) {
    const bf16* row = qkv + (size_t)(n * DD + s) * (3 * CC);
    q[head][s][dd] = b2f(row[head * HDIM + dd]);
    k[head][s][dd] = b2f(row[CC + head * HDIM + dd]);
    v[head][s][dd] = b2f(row[2 * CC + head * HDIM + dd]);
  }
  __syncthreads();
  for (int pair = dd; pair < 64; pair += 32) {
    int sq = pair >> 3, sk = pair & 7;
    float sum = 0.f;
#pragma unroll
    for (int e = 0; e < HDIM; e++) sum += q[head][sq][e] * k[head][sk][e];
    p[head][sq][sk] = sum * ATT_SCALE;
  }
  __syncthreads();
  if (dd < DD) {
    float mx = -1e30f;
    for (int sk = 0; sk < DD; sk++) mx = fmaxf(mx, p[head][dd][sk]);
    float sum = 0.f;
    for (int sk = 0; sk < DD; sk++) { float e = expf(p[head][dd][sk] - mx); p[head][dd][sk] = e; sum += e; }
    float inv = 1.0f / sum;
    for (int sk = 0; sk < DD; sk++) p[head][dd][sk] *= inv;
  }
  __syncthreads();
  for (int sq = 0; sq < DD; sq++) {
    float sum = 0.f;
#pragma unroll
    for (int sk = 0; sk < DD; sk++) sum += p[head][sq][sk] * v[head][sk][dd];
    O[(size_t)(n * DD + sq) * CC + head * HDIM + dd] = f2b(sum);
  }
}

// ---------------------------------------------------------------------------
// Fused time epilogue + space ln1:
//   X1T[m,c] = x[c,d,h,w] + lnf(T)[r,c]   (r = hw*8+d, m = d*1024+hw)
//   Y[m,c]   = s_ln1(X1T row)
// ---------------------------------------------------------------------------
__global__ void epi_ln1_kernel(const float* __restrict__ T, const void* __restrict__ x,
                               const void* __restrict__ gf, const void* __restrict__ bf,
                               const void* __restrict__ g1, const void* __restrict__ b1,
                               float* __restrict__ X1T, bf16* __restrict__ Y,
                               const int* __restrict__ dfl) {
  int f32 = *dfl;
  int wave = (blockIdx.x * blockDim.x + threadIdx.x) >> 6;
  int lane = threadIdx.x & 63;
  if (wave >= NTOK) return;
  const float* r = T + (size_t)wave * CC;
  float v0 = r[lane], v1 = r[lane + 64], v2 = r[lane + 128];
  float s = v0 + v1 + v2;
  for (int off = 32; off; off >>= 1) s += __shfl_xor(s, off);
  float mean = s * (1.0f / CC);
  float d0 = v0 - mean, d1 = v1 - mean, d2 = v2 - mean;
  float q = d0 * d0 + d1 * d1 + d2 * d2;
  for (int off = 32; off; off >>= 1) q += __shfl_xor(q, off);
  float rstd = rsqrtf(q * (1.0f / CC) + 1e-5f);
  int d = wave & 7, hw = wave >> 3;
  int m = d * 1024 + hw;
  float xv[3];
#pragma unroll
  for (int e = 0; e < 3; e++) {
    int c = lane + e * 64;
    float dv = (e == 0 ? d0 : (e == 1 ? d1 : d2));
    float normed = dv * rstd * ldin(gf, c, f32) + ldin(bf, c, f32);
    xv[e] = ldin(x, (size_t)((c << 3) + d) * 1024 + hw, f32) + normed;
  }
  float* o = X1T + (size_t)m * CC;
#pragma unroll
  for (int e = 0; e < 3; e++) o[lane + e * 64] = xv[e];
  // second LN (s_ln1) on xv row
  float s2 = xv[0] + xv[1] + xv[2];
  for (int off = 32; off; off >>= 1) s2 += __shfl_xor(s2, off);
  float mean2 = s2 * (1.0f / CC);
  float e0 = xv[0] - mean2, e1 = xv[1] - mean2, e2 = xv[2] - mean2;
  float q2 = e0 * e0 + e1 * e1 + e2 * e2;
  for (int off = 32; off; off >>= 1) q2 += __shfl_xor(q2, off);
  float rstd2 = rsqrtf(q2 * (1.0f / CC) + 1e-5f);
  bf16* y = Y + (size_t)m * CC;
  y[lane]       = f2b(e0 * rstd2 * ldin(g1, lane, f32)       + ldin(b1, lane, f32));
  y[lane + 64]  = f2b(e1 * rstd2 * ldin(g1, lane + 64, f32)  + ldin(b1, lane + 64, f32));
  y[lane + 128] = f2b(e2 * rstd2 * ldin(g1, lane + 128, f32) + ldin(b1, lane + 128, f32));
}

// ---------------------------------------------------------------------------
// NAT attention v3: XCD-aware swizzle — each XCD owns one d-frame so its
// 1.18 MB qkv slice stays hot in that XCD's 4 MiB L2.
// ---------------------------------------------------------------------------
__global__ void nat_attn_kernel(const bf16* __restrict__ qkv, const void* __restrict__ rpb,
                                bf16* __restrict__ O, const int* __restrict__ dfl) {
  int f32 = *dfl;
  __shared__ float qs[NHEAD][HDIM];
  __shared__ float sc[NHEAD][52];
  int blk = blockIdx.x;
  int m = ((blk & 7) << 10) | (blk >> 3);   // frame = blk%8 -> same XCD
  int d = m >> 10;
  int hw = m & 1023;
  int hy = hw >> 5, wx = hw & 31;
  int h = threadIdx.x >> 5;
  int l = threadIdx.x & 31;
  int sh = min(max(hy - 3, 0), HH - 7);
  int sw = min(max(wx - 3, 0), WW - 7);

  qs[h][l] = b2f(qkv[(size_t)m * (3 * CC) + h * HDIM + l]) * ATT_SCALE;
  __syncthreads();

  for (int j = l; j < 49; j += 32) {
    int a = j / 7, bb = j - a * 7;
    int ih = sh + a, iw = sw + bb;
    int mn = d * 1024 + ih * 32 + iw;
    const uint4* kru = reinterpret_cast<const uint4*>(
        qkv + (size_t)mn * (3 * CC) + CC + h * HDIM);
    float sum = 0.f;
#pragma unroll
    for (int c4 = 0; c4 < 4; c4++) {
      uint4 u = kru[c4];
      unsigned arr[4] = {u.x, u.y, u.z, u.w};
#pragma unroll
      for (int q2 = 0; q2 < 4; q2++) {
        unsigned uu = arr[q2];
        int dd = c4 * 8 + q2 * 2;
        sum += qs[h][dd]     * us2f((unsigned short)(uu & 0xffffu));
        sum += qs[h][dd + 1] * us2f((unsigned short)(uu >> 16));
      }
    }
    float bias = ldin(rpb, (size_t)h * 169 + (ih - hy + 6) * 13 + (iw - wx + 6), f32);
    sc[h][j] = sum + bias;
  }
  __syncthreads();

  float mx = -1e30f;
  for (int j = l; j < 49; j += 32) mx = fmaxf(mx, sc[h][j]);
  for (int off = 16; off; off >>= 1) mx = fmaxf(mx, __shfl_xor(mx, off, 32));
  float sum = 0.f;
  float e0 = 0.f, e1 = 0.f;
  {
    e0 = expf(sc[h][l] - mx);
    sum = e0;
    if (l < 17) { e1 = expf(sc[h][l + 32] - mx); sum += e1; }
  }
  for (int off = 16; off; off >>= 1) sum += __shfl_xor(sum, off, 32);
  float inv = 1.0f / sum;
  sc[h][l] = e0 * inv;
  if (l < 17) sc[h][l + 32] = e1 * inv;
  __syncthreads();

  float acc = 0.f;
  for (int j = 0; j < 49; j++) {
    int a = j / 7, bb = j - a * 7;
    int mn = d * 1024 + (sh + a) * 32 + (sw + bb);
    acc += sc[h][j] * b2f(qkv[(size_t)mn * (3 * CC) + 2 * CC + h * HDIM + l]);
  }
  O[(size_t)m * CC + h * HDIM + l] = f2b(acc);
}

// ---------------------------------------------------------------------------
extern "C" void kernel_launch(void* const* d_in, const int* in_sizes, int n_in,
                              void* d_out, int out_size, void* d_ws, size_t ws_size,
                              hipStream_t stream) {
  const void* x        = d_in[0];
  const void* pos_emb  = d_in[1];
  const void* t_ln1_g  = d_in[2];
  const void* t_ln1_b  = d_in[3];
  const void* t_qkv_w  = d_in[4];
  const void* t_out_w  = d_in[5];
  const void* t_out_b  = d_in[6];
  const void* t_ln2_g  = d_in[7];
  const void* t_ln2_b  = d_in[8];
  const void* t_fc1_w  = d_in[9];
  const void* t_fc1_b  = d_in[10];
  const void* t_fc2_w  = d_in[11];
  const void* t_fc2_b  = d_in[12];
  const void* t_lnf_g  = d_in[13];
  const void* t_lnf_b  = d_in[14];
  const void* s_ln1_g  = d_in[15];
  const void* s_ln1_b  = d_in[16];
  const void* s_qkv_w  = d_in[17];
  const void* s_qkv_b  = d_in[18];
  const void* s_rpb    = d_in[19];
  const void* s_proj_w = d_in[20];
  const void* s_proj_b = d_in[21];
  const void* s_ln2_g  = d_in[22];
  const void* s_ln2_b  = d_in[23];
  const void* s_fc1_w  = d_in[24];
  const void* s_fc1_b  = d_in[25];
  const void* s_fc2_w  = d_in[26];
  const void* s_fc2_b  = d_in[27];

  // Workspace (SZ = 8192*192):
  //   [0,SZ) f32 T/S | [SZ,2SZ) f32 X1T | [2SZ,2.5SZ) bf16 Y | [2.5SZ,3SZ) bf16 O
  //   [3SZ,5SZ) bf16 QKV/Hb | [5SZ] int dtype flag.  Total ~31.5 MB.
  float* ws = (float*)d_ws;
  const size_t SZ = (size_t)NTOK * CC;
  const size_t need = (5 * SZ + 4) * sizeof(float);
  if (ws_size < need) return;

  float* T   = ws;
  float* X1T = ws + SZ;
  bf16*  Y   = (bf16*)(ws + 2 * SZ);
  bf16*  O   = (bf16*)(ws + 2 * SZ + SZ / 2);
  bf16*  QKV = (bf16*)(ws + 3 * SZ);
  bf16*  Hb  = QKV;
  float* S   = T;
  int*   dfl = (int*)(ws + 5 * SZ);

  dim3 blk256(256);

  probe_dtype_kernel<<<1, 64, 0, stream>>>((const unsigned short*)x, dfl);

  // ---- Time transformer ----
  build_ln1_kernel<<<NTOK / 4, blk256, 0, stream>>>(x, pos_emb, t_ln1_g, t_ln1_b, T, Y, dfl);
  gemm_kernel<false, false, false, true, false><<<dim3(9, 64), blk256, 0, stream>>>(
      Y, t_qkv_w, nullptr, nullptr, QKV, nullptr, NTOK, 3 * CC, CC, dfl);
  time_attn_kernel<<<1024, 192, 0, stream>>>(QKV, O);
  gemm_kernel<true, false, true, false, false><<<dim3(3, 64), blk256, 0, stream>>>(
      O, t_out_w, t_out_b, T, T, nullptr, NTOK, CC, CC, dfl);
  ln_kernel<<<NTOK / 4, blk256, 0, stream>>>(T, Y, t_ln2_g, t_ln2_b, NTOK, dfl);
  gemm_kernel<true, true, false, true, false><<<dim3(12, 64), blk256, 0, stream>>>(
      Y, t_fc1_w, t_fc1_b, nullptr, Hb, nullptr, NTOK, HID, CC, dfl);
  gemm_kernel<true, false, true, false, false><<<dim3(3, 64), blk256, 0, stream>>>(
      Hb, t_fc2_w, t_fc2_b, T, T, nullptr, NTOK, CC, HID, dfl);
  epi_ln1_kernel<<<NTOK / 4, blk256, 0, stream>>>(
      T, x, t_lnf_g, t_lnf_b, s_ln1_g, s_ln1_b, X1T, Y, dfl);

  // ---- Space transformer ----
  gemm_kernel<true, false, false, true, false><<<dim3(9, 64), blk256, 0, stream>>>(
      Y, s_qkv_w, s_qkv_b, nullptr, QKV, nullptr, NTOK, 3 * CC, CC, dfl);
  nat_attn_kernel<<<NTOK, 192, 0, stream>>>(QKV, s_rpb, O, dfl);
  gemm_kernel<true, false, true, false, false><<<dim3(3, 64), blk256, 0, stream>>>(
      O, s_proj_w, s_proj_b, X1T, S, nullptr, NTOK, CC, CC, dfl);
  ln_kernel<<<NTOK / 4, blk256, 0, stream>>>(S, Y, s_ln2_g, s_ln2_b, NTOK, dfl);
  gemm_kernel<true, true, false, true, false><<<dim3(12, 64), blk256, 0, stream>>>(
      Y, s_fc1_w, s_fc1_b, nullptr, Hb, nullptr, NTOK, HID, CC, dfl);
  // last GEMM fused with final add: out[c*8192+m] = X1T + S + fc2(Hb)
  gemm_kernel<true, false, true, false, true><<<dim3(3, 64), blk256, 0, stream>>>(
      Hb, s_fc2_w, s_fc2_b, S, d_out, X1T, NTOK, CC, HID, dfl);
}

// Round 6
// 304.605 us; speedup vs baseline: 2.6987x; 1.1349x over previous
//
#include <hip/hip_runtime.h>
#include <hip/hip_bf16.h>
#include <math.h>

typedef __hip_bfloat16 bf16;
typedef short bf16x8 __attribute__((ext_vector_type(8)));
typedef float f32x4 __attribute__((ext_vector_type(4)));

__device__ __forceinline__ float b2f(bf16 v) { return __bfloat162float(v); }
__device__ __forceinline__ bf16 f2b(float v) { return __float2bfloat16(v); }
__device__ __forceinline__ float us2f(unsigned short u) {
  return __uint_as_float(((unsigned)u) << 16);
}
__device__ __forceinline__ unsigned short f2us(float f) {
  bf16 h = __float2bfloat16(f);
  return *reinterpret_cast<unsigned short*>(&h);
}
__device__ __forceinline__ float ldin(const void* p, size_t i, int f32) {
  return f32 ? ((const float*)p)[i] : b2f(((const bf16*)p)[i]);
}

#define CC 192
#define DD 8
#define HH 32
#define WW 32
#define NHEAD 6
#define HDIM 32
#define HID 768
#define NTOK 8192
#define ATT_SCALE 0.17677669529663687f

// ---------------------------------------------------------------------------
// Dtype probe (proven): flag=1 means inputs are fp32.
// ---------------------------------------------------------------------------
__global__ void probe_dtype_kernel(const unsigned short* __restrict__ xu,
                                   int* __restrict__ flag) {
  if (threadIdx.x == 0 && blockIdx.x == 0) {
    int insane = 0;
    for (int i = 0; i < 256; i++) {
      float v = us2f(xu[i]);
      float a = fabsf(v);
      bool sane = (a == 0.0f) || (a > 9.5e-7f && a < 64.0f);
      if (!sane) insane++;
    }
    *flag = (insane > 32) ? 1 : 0;
  }
}

// ---------------------------------------------------------------------------
// Fused: T[r,c] = x[c,d,h,w] + pos[d,c];  Y = LN(T)   (wave per row)
// ---------------------------------------------------------------------------
__global__ void build_ln1_kernel(const void* __restrict__ x, const void* __restrict__ pos,
                                 const void* __restrict__ g, const void* __restrict__ b,
                                 float* __restrict__ T, bf16* __restrict__ Y,
                                 const int* __restrict__ dfl) {
  int f32 = *dfl;
  int wave = (blockIdx.x * blockDim.x + threadIdx.x) >> 6;
  int lane = threadIdx.x & 63;
  if (wave >= NTOK) return;
  int d = wave & 7, hw = wave >> 3;
  float v[3];
#pragma unroll
  for (int e = 0; e < 3; e++) {
    int c = lane + e * 64;
    v[e] = ldin(x, (size_t)((c << 3) + d) * 1024 + hw, f32) +
           ldin(pos, (size_t)d * CC + c, f32);
  }
  float* tr = T + (size_t)wave * CC;
#pragma unroll
  for (int e = 0; e < 3; e++) tr[lane + e * 64] = v[e];
  float s = v[0] + v[1] + v[2];
  for (int off = 32; off; off >>= 1) s += __shfl_xor(s, off);
  float mean = s * (1.0f / CC);
  float d0 = v[0] - mean, d1 = v[1] - mean, d2 = v[2] - mean;
  float q = d0 * d0 + d1 * d1 + d2 * d2;
  for (int off = 32; off; off >>= 1) q += __shfl_xor(q, off);
  float rstd = rsqrtf(q * (1.0f / CC) + 1e-5f);
  bf16* o = Y + (size_t)wave * CC;
  o[lane]       = f2b(d0 * rstd * ldin(g, lane, f32)       + ldin(b, lane, f32));
  o[lane + 64]  = f2b(d1 * rstd * ldin(g, lane + 64, f32)  + ldin(b, lane + 64, f32));
  o[lane + 128] = f2b(d2 * rstd * ldin(g, lane + 128, f32) + ldin(b, lane + 128, f32));
}

// ---------------------------------------------------------------------------
// LayerNorm (standalone): fp32 in, bf16 out
// ---------------------------------------------------------------------------
__global__ void ln_kernel(const float* __restrict__ in, bf16* __restrict__ out,
                          const void* __restrict__ g, const void* __restrict__ b,
                          int rows, const int* __restrict__ dfl) {
  int f32 = *dfl;
  int wave = (blockIdx.x * blockDim.x + threadIdx.x) >> 6;
  int lane = threadIdx.x & 63;
  if (wave >= rows) return;
  const float* r = in + (size_t)wave * CC;
  float v0 = r[lane], v1 = r[lane + 64], v2 = r[lane + 128];
  float s = v0 + v1 + v2;
  for (int off = 32; off; off >>= 1) s += __shfl_xor(s, off);
  float mean = s * (1.0f / CC);
  float d0 = v0 - mean, d1 = v1 - mean, d2 = v2 - mean;
  float q = d0 * d0 + d1 * d1 + d2 * d2;
  for (int off = 32; off; off >>= 1) q += __shfl_xor(q, off);
  float rstd = rsqrtf(q * (1.0f / CC) + 1e-5f);
  bf16* o = out + (size_t)wave * CC;
  o[lane]       = f2b(d0 * rstd * ldin(g, lane, f32)       + ldin(b, lane, f32));
  o[lane + 64]  = f2b(d1 * rstd * ldin(g, lane + 64, f32)  + ldin(b, lane + 64, f32));
  o[lane + 128] = f2b(d2 * rstd * ldin(g, lane + 128, f32) + ldin(b, lane + 128, f32));
}

// ---------------------------------------------------------------------------
// MFMA GEMM, tile (TM*64)M x 64N, BK=32, 256 thr = 4 waves.
// TM=2: wave does 32 rows (2x4 frags). TM=1: wave does 16 rows (1x4 frags).
// FINAL: dst[col*NTOK+row] = v + X2[row*CC+col] (dtype by flag)
// ---------------------------------------------------------------------------
template <int TM, bool BIAS, bool GELU, bool RES, bool OUTBF, bool FINAL>
__global__ void gemm_kernel(const bf16* __restrict__ A, const void* __restrict__ W,
                            const void* __restrict__ bias, const float* __restrict__ R,
                            void* __restrict__ Cout, const float* __restrict__ X2,
                            int M, int N, int K, const int* __restrict__ dfl) {
  int f32 = *dfl;
  __shared__ __align__(16) unsigned short As[TM * 64 * 40];
  __shared__ __align__(16) unsigned short Bs[64 * 40];
  int bm = blockIdx.y * (TM * 64), bn = blockIdx.x * 64;
  int tid = threadIdx.x;
  int w = tid >> 6;
  int lane = tid & 63;
  int lm = lane & 15;
  int lk = lane >> 4;

  f32x4 acc[TM][4];
#pragma unroll
  for (int i = 0; i < TM; i++)
#pragma unroll
    for (int j = 0; j < 4; j++) acc[i][j] = (f32x4){0.f, 0.f, 0.f, 0.f};

  const unsigned short* Au = reinterpret_cast<const unsigned short*>(A);

  for (int k0 = 0; k0 < K; k0 += 32) {
#pragma unroll
    for (int u = 0; u < TM; u++) {
      int unit = tid + u * 256;
      int row = unit >> 2, seg = unit & 3;
      uint4 v = *reinterpret_cast<const uint4*>(
          &Au[(size_t)(bm + row) * K + k0 + seg * 8]);
      *reinterpret_cast<uint4*>(&As[row * 40 + seg * 8]) = v;
    }
    {
      int e0 = tid * 8;
      int kk = e0 >> 6, n0 = e0 & 63;
      unsigned short vals[8];
      if (f32) {
        const float* Wf = (const float*)W + (size_t)(k0 + kk) * N + bn + n0;
        float4 w0 = *reinterpret_cast<const float4*>(Wf);
        float4 w1 = *reinterpret_cast<const float4*>(Wf + 4);
        vals[0] = f2us(w0.x); vals[1] = f2us(w0.y); vals[2] = f2us(w0.z); vals[3] = f2us(w0.w);
        vals[4] = f2us(w1.x); vals[5] = f2us(w1.y); vals[6] = f2us(w1.z); vals[7] = f2us(w1.w);
      } else {
        const unsigned short* Wb = (const unsigned short*)W + (size_t)(k0 + kk) * N + bn + n0;
        ushort4 u0 = *reinterpret_cast<const ushort4*>(Wb);
        ushort4 u1 = *reinterpret_cast<const ushort4*>(Wb + 4);
        vals[0] = u0.x; vals[1] = u0.y; vals[2] = u0.z; vals[3] = u0.w;
        vals[4] = u1.x; vals[5] = u1.y; vals[6] = u1.z; vals[7] = u1.w;
      }
#pragma unroll
      for (int j = 0; j < 8; j++) Bs[(n0 + j) * 40 + kk] = vals[j];
    }
    __syncthreads();

    bf16x8 af[TM], bfr[4];
#pragma unroll
    for (int tm = 0; tm < TM; tm++)
      af[tm] = *reinterpret_cast<const bf16x8*>(
          &As[(w * (TM * 16) + tm * 16 + lm) * 40 + lk * 8]);
#pragma unroll
    for (int tn = 0; tn < 4; tn++)
      bfr[tn] = *reinterpret_cast<const bf16x8*>(
          &Bs[(tn * 16 + lm) * 40 + lk * 8]);
#pragma unroll
    for (int tm = 0; tm < TM; tm++)
#pragma unroll
      for (int tn = 0; tn < 4; tn++)
        acc[tm][tn] = __builtin_amdgcn_mfma_f32_16x16x32_bf16(
            af[tm], bfr[tn], acc[tm][tn], 0, 0, 0);
    __syncthreads();
  }

#pragma unroll
  for (int tn = 0; tn < 4; tn++) {
    int col = bn + tn * 16 + lm;
    float bv = BIAS ? ldin(bias, col, f32) : 0.f;
#pragma unroll
    for (int tm = 0; tm < TM; tm++) {
      int row0 = bm + w * (TM * 16) + tm * 16 + lk * 4;
#pragma unroll
      for (int r = 0; r < 4; r++) {
        int row = row0 + r;
        float v = acc[tm][tn][r];
        if (BIAS) v += bv;
        if (GELU) v = 0.5f * v * (1.0f + erff(v * 0.70710678118654752f));
        size_t idx = (size_t)row * N + col;
        if (RES) v += R[idx];
        if (FINAL) {
          float o = v + X2[(size_t)row * CC + col];
          if (f32) ((float*)Cout)[(size_t)col * NTOK + row] = o;
          else     ((bf16*)Cout)[(size_t)col * NTOK + row] = f2b(o);
        } else if (OUTBF) {
          ((bf16*)Cout)[idx] = f2b(v);
        } else {
          ((float*)Cout)[idx] = v;
        }
      }
    }
  }
}

// ---------------------------------------------------------------------------
// Time attention: one block per sequence n (1024), 192 threads
// ---------------------------------------------------------------------------
__global__ void time_attn_kernel(const bf16* __restrict__ qkv, bf16* __restrict__ O) {
  __shared__ float q[NHEAD][DD][HDIM];
  __shared__ float k[NHEAD][DD][HDIM];
  __shared__ float v[NHEAD][DD][HDIM];
  __shared__ float p[NHEAD][DD][DD];
  int n = blockIdx.x;
  int head = threadIdx.x >> 5;
  int dd = threadIdx.x & 31;
  for (int s = 0; s < DD; s++) {
    const bf16* row = qkv + (size_t)(n * DD + s) * (3 * CC);
    q[head][s][dd] = b2f(row[head * HDIM + dd]);
    k[head][s][dd] = b2f(row[CC + head * HDIM + dd]);
    v[head][s][dd] = b2f(row[2 * CC + head * HDIM + dd]);
  }
  __syncthreads();
  for (int pair = dd; pair < 64; pair += 32) {
    int sq = pair >> 3, sk = pair & 7;
    float sum = 0.f;
#pragma unroll
    for (int e = 0; e < HDIM; e++) sum += q[head][sq][e] * k[head][sk][e];
    p[head][sq][sk] = sum * ATT_SCALE;
  }
  __syncthreads();
  if (dd < DD) {
    float mx = -1e30f;
    for (int sk = 0; sk < DD; sk++) mx = fmaxf(mx, p[head][dd][sk]);
    float sum = 0.f;
    for (int sk = 0; sk < DD; sk++) { float e = expf(p[head][dd][sk] - mx); p[head][dd][sk] = e; sum += e; }
    float inv = 1.0f / sum;
    for (int sk = 0; sk < DD; sk++) p[head][dd][sk] *= inv;
  }
  __syncthreads();
  for (int sq = 0; sq < DD; sq++) {
    float sum = 0.f;
#pragma unroll
    for (int sk = 0; sk < DD; sk++) sum += p[head][sq][sk] * v[head][sk][dd];
    O[(size_t)(n * DD + sq) * CC + head * HDIM + dd] = f2b(sum);
  }
}

// ---------------------------------------------------------------------------
// Fused time epilogue + space ln1
// ---------------------------------------------------------------------------
__global__ void epi_ln1_kernel(const float* __restrict__ T, const void* __restrict__ x,
                               const void* __restrict__ gf, const void* __restrict__ bf,
                               const void* __restrict__ g1, const void* __restrict__ b1,
                               float* __restrict__ X1T, bf16* __restrict__ Y,
                               const int* __restrict__ dfl) {
  int f32 = *dfl;
  int wave = (blockIdx.x * blockDim.x + threadIdx.x) >> 6;
  int lane = threadIdx.x & 63;
  if (wave >= NTOK) return;
  const float* r = T + (size_t)wave * CC;
  float v0 = r[lane], v1 = r[lane + 64], v2 = r[lane + 128];
  float s = v0 + v1 + v2;
  for (int off = 32; off; off >>= 1) s += __shfl_xor(s, off);
  float mean = s * (1.0f / CC);
  float d0 = v0 - mean, d1 = v1 - mean, d2 = v2 - mean;
  float q = d0 * d0 + d1 * d1 + d2 * d2;
  for (int off = 32; off; off >>= 1) q += __shfl_xor(q, off);
  float rstd = rsqrtf(q * (1.0f / CC) + 1e-5f);
  int d = wave & 7, hw = wave >> 3;
  int m = d * 1024 + hw;
  float xv[3];
#pragma unroll
  for (int e = 0; e < 3; e++) {
    int c = lane + e * 64;
    float dv = (e == 0 ? d0 : (e == 1 ? d1 : d2));
    float normed = dv * rstd * ldin(gf, c, f32) + ldin(bf, c, f32);
    xv[e] = ldin(x, (size_t)((c << 3) + d) * 1024 + hw, f32) + normed;
  }
  float* o = X1T + (size_t)m * CC;
#pragma unroll
  for (int e = 0; e < 3; e++) o[lane + e * 64] = xv[e];
  float s2 = xv[0] + xv[1] + xv[2];
  for (int off = 32; off; off >>= 1) s2 += __shfl_xor(s2, off);
  float mean2 = s2 * (1.0f / CC);
  float e0 = xv[0] - mean2, e1 = xv[1] - mean2, e2 = xv[2] - mean2;
  float q2 = e0 * e0 + e1 * e1 + e2 * e2;
  for (int off = 32; off; off >>= 1) q2 += __shfl_xor(q2, off);
  float rstd2 = rsqrtf(q2 * (1.0f / CC) + 1e-5f);
  bf16* y = Y + (size_t)m * CC;
  y[lane]       = f2b(e0 * rstd2 * ldin(g1, lane, f32)       + ldin(b1, lane, f32));
  y[lane + 64]  = f2b(e1 * rstd2 * ldin(g1, lane + 64, f32)  + ldin(b1, lane + 64, f32));
  y[lane + 128] = f2b(e2 * rstd2 * ldin(g1, lane + 128, f32) + ldin(b1, lane + 128, f32));
}

// ---------------------------------------------------------------------------
// MFMA NAT attention. Block = (frame, 8x8 query tile, head); 768 blocks,
// 256 thr = 4 waves, wave = 16 queries. 14x14=196-key neighborhood (union
// of all clamped 7x7 windows of the tile), padded to 224 keys.
// Scores via mfma_16x16x32 (K=32=HDIM, 1 mfma per 16x16 tile); bias+mask in
// C-layout regs; row softmax (in-reg + 4 shfl steps); P->LDS->A-layout; PV
// via 14 mfma. XCD swizzle: frame = blk&7.
// ---------------------------------------------------------------------------
#define NKEY 224          // padded keys
#define PKS 40            // Ks/Qs row stride (elems)
#define PVS 232           // Vs/Ps row stride (elems)
__global__ void nat_attn_kernel(const bf16* __restrict__ qkv, const void* __restrict__ rpb,
                                bf16* __restrict__ O, const int* __restrict__ dfl) {
  int f32 = *dfl;
  __shared__ __align__(16) unsigned short Ks[NKEY * PKS];
  __shared__ __align__(16) unsigned short Vs[32 * PVS];
  __shared__ __align__(16) unsigned short Qs[64 * PKS];
  __shared__ __align__(16) unsigned short Ps[64 * PVS];
  __shared__ float rb[176];

  int blk = blockIdx.x;
  int frame = blk & 7;
  int rest = blk >> 3;          // 0..95
  int h = rest % 6;
  int tile = rest / 6;          // 0..15
  int ty = tile >> 2, tx = tile & 3;
  int base_h = min(max(ty * 8 - 3, 0), HH - 7);
  int base_w = min(max(tx * 8 - 3, 0), WW - 7);

  int tid = threadIdx.x;

  // ---- stage rpb[h] ----
  for (int i = tid; i < 169; i += 256) rb[i] = ldin(rpb, (size_t)h * 169 + i, f32);
  // ---- stage K (196 keys x 32 dims; clamp OOB coords, masked later) ----
  for (int u = tid; u < 784; u += 256) {
    int j = u >> 2, seg = u & 3;
    int a = j / 14, bb = j - a * 14;
    int ih = min(base_h + a, HH - 1), iw = min(base_w + bb, WW - 1);
    int mg = frame * 1024 + ih * 32 + iw;
    uint4 v = *reinterpret_cast<const uint4*>(qkv + (size_t)mg * 576 + 192 + h * 32 + seg * 8);
    *reinterpret_cast<uint4*>(&Ks[j * PKS + seg * 8]) = v;
  }
  // ---- stage V transposed: Vs[dim][key] ----
  for (int u = tid; u < 784; u += 256) {
    int j = u >> 2, seg = u & 3;
    int a = j / 14, bb = j - a * 14;
    int ih = min(base_h + a, HH - 1), iw = min(base_w + bb, WW - 1);
    int mg = frame * 1024 + ih * 32 + iw;
    uint4 v = *reinterpret_cast<const uint4*>(qkv + (size_t)mg * 576 + 384 + h * 32 + seg * 8);
    unsigned arr[4] = {v.x, v.y, v.z, v.w};
#pragma unroll
    for (int e = 0; e < 4; e++) {
      Vs[(seg * 8 + e * 2) * PVS + j]     = (unsigned short)(arr[e] & 0xffffu);
      Vs[(seg * 8 + e * 2 + 1) * PVS + j] = (unsigned short)(arr[e] >> 16);
    }
  }
  // ---- zero V pad keys [196, PVS) ----
  for (int u = tid; u < 32 * (PVS - 196); u += 256) {
    int dd = u / (PVS - 196), c = 196 + u % (PVS - 196);
    Vs[dd * PVS + c] = 0;
  }
  // ---- stage Q (64 queries x 32 dims) ----
  {
    int q = tid >> 2, seg = tid & 3;
    int qy = ty * 8 + (q >> 3), qx = tx * 8 + (q & 7);
    int mg = frame * 1024 + qy * 32 + qx;
    uint4 v = *reinterpret_cast<const uint4*>(qkv + (size_t)mg * 576 + h * 32 + seg * 8);
    *reinterpret_cast<uint4*>(&Qs[q * PKS + seg * 8]) = v;
  }
  __syncthreads();

  int w = tid >> 6;
  int lane = tid & 63;
  int c = lane & 15;
  int lk = lane >> 4;

  // ---- scores: 14 MFMAs (one per 16-key tile) ----
  bf16x8 aq = *reinterpret_cast<const bf16x8*>(&Qs[(w * 16 + c) * PKS + lk * 8]);
  f32x4 sc[14];
#pragma unroll
  for (int f = 0; f < 14; f++) {
    bf16x8 bk = *reinterpret_cast<const bf16x8*>(&Ks[(f * 16 + c) * PKS + lk * 8]);
    sc[f] = __builtin_amdgcn_mfma_f32_16x16x32_bf16(aq, bk, (f32x4){0.f, 0.f, 0.f, 0.f}, 0, 0, 0);
  }

  // ---- scale + bias + window mask (C-layout: col=key=f*16+c, row=lk*4+r) ----
#pragma unroll
  for (int f = 0; f < 14; f++) {
    int key = f * 16 + c;
    int a = key / 14, bb = key - a * 14;
    int ih = base_h + a, iw = base_w + bb;
    bool keyok = key < 196;
#pragma unroll
    for (int r = 0; r < 4; r++) {
      int qloc = w * 16 + lk * 4 + r;
      int qy = ty * 8 + (qloc >> 3), qx = tx * 8 + (qloc & 7);
      int sh = min(max(qy - 3, 0), HH - 7);
      int sw = min(max(qx - 3, 0), WW - 7);
      bool valid = keyok && ((unsigned)(ih - sh) < 7u) && ((unsigned)(iw - sw) < 7u);
      int bidx = valid ? (ih - qy + 6) * 13 + (iw - qx + 6) : 0;
      float s = sc[f][r] * ATT_SCALE + rb[bidx];
      sc[f][r] = valid ? s : -1e30f;
    }
  }

  // ---- row softmax: reduce over 14 frags in-reg, then 16 lanes (xor 1,2,4,8) ----
  float mx[4], sm[4];
#pragma unroll
  for (int r = 0; r < 4; r++) {
    float m = sc[0][r];
#pragma unroll
    for (int f = 1; f < 14; f++) m = fmaxf(m, sc[f][r]);
    for (int off = 8; off; off >>= 1) m = fmaxf(m, __shfl_xor(m, off));
    mx[r] = m;
    float s = 0.f;
#pragma unroll
    for (int f = 0; f < 14; f++) { float e = __expf(sc[f][r] - m); sc[f][r] = e; s += e; }
    for (int off = 8; off; off >>= 1) s += __shfl_xor(s, off);
    sm[r] = 1.0f / s;
  }
  // ---- write P (A-layout source): Ps[q][key] ----
#pragma unroll
  for (int f = 0; f < 14; f++)
#pragma unroll
    for (int r = 0; r < 4; r++)
      Ps[(w * 16 + lk * 4 + r) * PVS + f * 16 + c] = f2us(sc[f][r] * sm[r]);
  __syncthreads();

  // ---- PV: 7 k-steps x 2 dim-tiles ----
  f32x4 oacc[2] = {(f32x4){0.f, 0.f, 0.f, 0.f}, (f32x4){0.f, 0.f, 0.f, 0.f}};
#pragma unroll
  for (int kt = 0; kt < 7; kt++) {
    bf16x8 ap = *reinterpret_cast<const bf16x8*>(&Ps[(w * 16 + c) * PVS + kt * 32 + lk * 8]);
#pragma unroll
    for (int dt = 0; dt < 2; dt++) {
      bf16x8 bv = *reinterpret_cast<const bf16x8*>(&Vs[(dt * 16 + c) * PVS + kt * 32 + lk * 8]);
      oacc[dt] = __builtin_amdgcn_mfma_f32_16x16x32_bf16(ap, bv, oacc[dt], 0, 0, 0);
    }
  }

  // ---- write O (C-layout: col=dim=dt*16+c, row=q=lk*4+r) ----
#pragma unroll
  for (int dt = 0; dt < 2; dt++)
#pragma unroll
    for (int r = 0; r < 4; r++) {
      int qloc = w * 16 + lk * 4 + r;
      int qy = ty * 8 + (qloc >> 3), qx = tx * 8 + (qloc & 7);
      int mg = frame * 1024 + qy * 32 + qx;
      O[(size_t)mg * CC + h * 32 + dt * 16 + c] = f2b(oacc[dt][r]);
    }
}

// ---------------------------------------------------------------------------
extern "C" void kernel_launch(void* const* d_in, const int* in_sizes, int n_in,
                              void* d_out, int out_size, void* d_ws, size_t ws_size,
                              hipStream_t stream) {
  const void* x        = d_in[0];
  const void* pos_emb  = d_in[1];
  const void* t_ln1_g  = d_in[2];
  const void* t_ln1_b  = d_in[3];
  const void* t_qkv_w  = d_in[4];
  const void* t_out_w  = d_in[5];
  const void* t_out_b  = d_in[6];
  const void* t_ln2_g  = d_in[7];
  const void* t_ln2_b  = d_in[8];
  const void* t_fc1_w  = d_in[9];
  const void* t_fc1_b  = d_in[10];
  const void* t_fc2_w  = d_in[11];
  const void* t_fc2_b  = d_in[12];
  const void* t_lnf_g  = d_in[13];
  const void* t_lnf_b  = d_in[14];
  const void* s_ln1_g  = d_in[15];
  const void* s_ln1_b  = d_in[16];
  const void* s_qkv_w  = d_in[17];
  const void* s_qkv_b  = d_in[18];
  const void* s_rpb    = d_in[19];
  const void* s_proj_w = d_in[20];
  const void* s_proj_b = d_in[21];
  const void* s_ln2_g  = d_in[22];
  const void* s_ln2_b  = d_in[23];
  const void* s_fc1_w  = d_in[24];
  const void* s_fc1_b  = d_in[25];
  const void* s_fc2_w  = d_in[26];
  const void* s_fc2_b  = d_in[27];

  float* ws = (float*)d_ws;
  const size_t SZ = (size_t)NTOK * CC;
  const size_t need = (5 * SZ + 4) * sizeof(float);
  if (ws_size < need) return;

  float* T   = ws;
  float* X1T = ws + SZ;
  bf16*  Y   = (bf16*)(ws + 2 * SZ);
  bf16*  O   = (bf16*)(ws + 2 * SZ + SZ / 2);
  bf16*  QKV = (bf16*)(ws + 3 * SZ);
  bf16*  Hb  = QKV;
  float* S   = T;
  int*   dfl = (int*)(ws + 5 * SZ);

  dim3 blk256(256);

  probe_dtype_kernel<<<1, 64, 0, stream>>>((const unsigned short*)x, dfl);

  // ---- Time transformer ----
  build_ln1_kernel<<<NTOK / 4, blk256, 0, stream>>>(x, pos_emb, t_ln1_g, t_ln1_b, T, Y, dfl);
  gemm_kernel<2, false, false, false, true, false><<<dim3(9, 64), blk256, 0, stream>>>(
      Y, t_qkv_w, nullptr, nullptr, QKV, nullptr, NTOK, 3 * CC, CC, dfl);
  time_attn_kernel<<<1024, 192, 0, stream>>>(QKV, O);
  gemm_kernel<1, true, false, true, false, false><<<dim3(3, 128), blk256, 0, stream>>>(
      O, t_out_w, t_out_b, T, T, nullptr, NTOK, CC, CC, dfl);
  ln_kernel<<<NTOK / 4, blk256, 0, stream>>>(T, Y, t_ln2_g, t_ln2_b, NTOK, dfl);
  gemm_kernel<2, true, true, false, true, false><<<dim3(12, 64), blk256, 0, stream>>>(
      Y, t_fc1_w, t_fc1_b, nullptr, Hb, nullptr, NTOK, HID, CC, dfl);
  gemm_kernel<1, true, false, true, false, false><<<dim3(3, 128), blk256, 0, stream>>>(
      Hb, t_fc2_w, t_fc2_b, T, T, nullptr, NTOK, CC, HID, dfl);
  epi_ln1_kernel<<<NTOK / 4, blk256, 0, stream>>>(
      T, x, t_lnf_g, t_lnf_b, s_ln1_g, s_ln1_b, X1T, Y, dfl);

  // ---- Space transformer ----
  gemm_kernel<2, true, false, false, true, false><<<dim3(9, 64), blk256, 0, stream>>>(
      Y, s_qkv_w, s_qkv_b, nullptr, QKV, nullptr, NTOK, 3 * CC, CC, dfl);
  nat_attn_kernel<<<768, blk256, 0, stream>>>(QKV, s_rpb, O, dfl);
  gemm_kernel<1, true, false, true, false, false><<<dim3(3, 128), blk256, 0, stream>>>(
      O, s_proj_w, s_proj_b, X1T, S, nullptr, NTOK, CC, CC, dfl);
  ln_kernel<<<NTOK / 4, blk256, 0, stream>>>(S, Y, s_ln2_g, s_ln2_b, NTOK, dfl);
  gemm_kernel<2, true, true, false, true, false><<<dim3(12, 64), blk256, 0, stream>>>(
      Y, s_fc1_w, s_fc1_b, nullptr, Hb, nullptr, NTOK, HID, CC, dfl);
  gemm_kernel<1, true, false, true, false, true><<<dim3(3, 128), blk256, 0, stream>>>(
      Hb, s_fc2_w, s_fc2_b, S, d_out, X1T, NTOK, CC, HID, dfl);
}

// Round 7
// 279.666 us; speedup vs baseline: 2.9394x; 1.0892x over previous
//
#include <hip/hip_runtime.h>
#include <hip/hip_bf16.h>
#include <math.h>

typedef __hip_bfloat16 bf16;
typedef short bf16x8 __attribute__((ext_vector_type(8)));
typedef float f32x4 __attribute__((ext_vector_type(4)));

__device__ __forceinline__ float b2f(bf16 v) { return __bfloat162float(v); }
__device__ __forceinline__ bf16 f2b(float v) { return __float2bfloat16(v); }
__device__ __forceinline__ float us2f(unsigned short u) {
  return __uint_as_float(((unsigned)u) << 16);
}
__device__ __forceinline__ unsigned short f2us(float f) {
  bf16 h = __float2bfloat16(f);
  return *reinterpret_cast<unsigned short*>(&h);
}
__device__ __forceinline__ float ldin(const void* p, size_t i, int f32) {
  return f32 ? ((const float*)p)[i] : b2f(((const bf16*)p)[i]);
}

#define CC 192
#define DD 8
#define HH 32
#define WW 32
#define NHEAD 6
#define HDIM 32
#define HID 768
#define NTOK 8192
#define ATT_SCALE 0.17677669529663687f

// ---------------------------------------------------------------------------
// Dtype probe, parallel: 64 lanes x 4 loads, wave-reduce. flag=1 -> fp32.
// ---------------------------------------------------------------------------
__global__ void probe_dtype_kernel(const unsigned short* __restrict__ xu,
                                   int* __restrict__ flag) {
  int lane = threadIdx.x;
  int insane = 0;
  for (int i = lane; i < 256; i += 64) {
    float a = fabsf(us2f(xu[i]));
    bool sane = (a == 0.0f) || (a > 9.5e-7f && a < 64.0f);
    if (!sane) insane++;
  }
  for (int off = 32; off; off >>= 1) insane += __shfl_xor(insane, off);
  if (lane == 0) *flag = (insane > 32) ? 1 : 0;
}

// ---------------------------------------------------------------------------
// Weight pre-pass: convert 8 matrices to bf16 transposed [N,K] in workspace.
// WT[woff + n*K + k] = W[k*N + n].  Total 884736 elems.
// ---------------------------------------------------------------------------
__global__ void wconv_kernel(const void* w0, const void* w1, const void* w2,
                             const void* w3, const void* w4, const void* w5,
                             const void* w6, const void* w7,
                             bf16* __restrict__ WT, const int* __restrict__ dfl) {
  int f32 = *dfl;
  int idx = blockIdx.x * 256 + threadIdx.x;
  if (idx >= 884736) return;
  const void* src; int K, N, loc;
  if      (idx < 110592) { src = w0; K = 192; N = 576; loc = idx; }
  else if (idx < 147456) { src = w1; K = 192; N = 192; loc = idx - 110592; }
  else if (idx < 294912) { src = w2; K = 192; N = 768; loc = idx - 147456; }
  else if (idx < 442368) { src = w3; K = 768; N = 192; loc = idx - 294912; }
  else if (idx < 552960) { src = w4; K = 192; N = 576; loc = idx - 442368; }
  else if (idx < 589824) { src = w5; K = 192; N = 192; loc = idx - 552960; }
  else if (idx < 737280) { src = w6; K = 192; N = 768; loc = idx - 589824; }
  else                   { src = w7; K = 768; N = 192; loc = idx - 737280; }
  int n = loc / K, k = loc - n * K;
  WT[idx] = f2b(ldin(src, (size_t)k * N + n, f32));
}

// WT element offsets (see wconv):
#define WOFF_TQKV  0
#define WOFF_TOUT  110592
#define WOFF_TFC1  147456
#define WOFF_TFC2  294912
#define WOFF_SQKV  442368
#define WOFF_SPROJ 552960
#define WOFF_SFC1  589824
#define WOFF_SFC2  737280

// ---------------------------------------------------------------------------
// Fused: T[r,c] = x[c,d,h,w] + pos[d,c];  Y = LN(T)   (wave per row)
// ---------------------------------------------------------------------------
__global__ void build_ln1_kernel(const void* __restrict__ x, const void* __restrict__ pos,
                                 const void* __restrict__ g, const void* __restrict__ b,
                                 float* __restrict__ T, bf16* __restrict__ Y,
                                 const int* __restrict__ dfl) {
  int f32 = *dfl;
  int wave = (blockIdx.x * blockDim.x + threadIdx.x) >> 6;
  int lane = threadIdx.x & 63;
  if (wave >= NTOK) return;
  int d = wave & 7, hw = wave >> 3;
  float v[3];
#pragma unroll
  for (int e = 0; e < 3; e++) {
    int c = lane + e * 64;
    v[e] = ldin(x, (size_t)((c << 3) + d) * 1024 + hw, f32) +
           ldin(pos, (size_t)d * CC + c, f32);
  }
  float* tr = T + (size_t)wave * CC;
#pragma unroll
  for (int e = 0; e < 3; e++) tr[lane + e * 64] = v[e];
  float s = v[0] + v[1] + v[2];
  for (int off = 32; off; off >>= 1) s += __shfl_xor(s, off);
  float mean = s * (1.0f / CC);
  float d0 = v[0] - mean, d1 = v[1] - mean, d2 = v[2] - mean;
  float q = d0 * d0 + d1 * d1 + d2 * d2;
  for (int off = 32; off; off >>= 1) q += __shfl_xor(q, off);
  float rstd = rsqrtf(q * (1.0f / CC) + 1e-5f);
  bf16* o = Y + (size_t)wave * CC;
  o[lane]       = f2b(d0 * rstd * ldin(g, lane, f32)       + ldin(b, lane, f32));
  o[lane + 64]  = f2b(d1 * rstd * ldin(g, lane + 64, f32)  + ldin(b, lane + 64, f32));
  o[lane + 128] = f2b(d2 * rstd * ldin(g, lane + 128, f32) + ldin(b, lane + 128, f32));
}

// ---------------------------------------------------------------------------
// LayerNorm (standalone): fp32 in, bf16 out
// ---------------------------------------------------------------------------
__global__ void ln_kernel(const float* __restrict__ in, bf16* __restrict__ out,
                          const void* __restrict__ g, const void* __restrict__ b,
                          int rows, const int* __restrict__ dfl) {
  int f32 = *dfl;
  int wave = (blockIdx.x * blockDim.x + threadIdx.x) >> 6;
  int lane = threadIdx.x & 63;
  if (wave >= rows) return;
  const float* r = in + (size_t)wave * CC;
  float v0 = r[lane], v1 = r[lane + 64], v2 = r[lane + 128];
  float s = v0 + v1 + v2;
  for (int off = 32; off; off >>= 1) s += __shfl_xor(s, off);
  float mean = s * (1.0f / CC);
  float d0 = v0 - mean, d1 = v1 - mean, d2 = v2 - mean;
  float q = d0 * d0 + d1 * d1 + d2 * d2;
  for (int off = 32; off; off >>= 1) q += __shfl_xor(q, off);
  float rstd = rsqrtf(q * (1.0f / CC) + 1e-5f);
  bf16* o = out + (size_t)wave * CC;
  o[lane]       = f2b(d0 * rstd * ldin(g, lane, f32)       + ldin(b, lane, f32));
  o[lane + 64]  = f2b(d1 * rstd * ldin(g, lane + 64, f32)  + ldin(b, lane + 64, f32));
  o[lane + 128] = f2b(d2 * rstd * ldin(g, lane + 128, f32) + ldin(b, lane + 128, f32));
}

// ---------------------------------------------------------------------------
// MFMA GEMM v2: A bf16 [M,K], WT bf16 [N,K] (pre-transposed). BK=64.
// Tile (TM*64)M x 64N, 256 thr = 4 waves; per k-iter 2 k-chunks of 8 MFMA.
// LDS row stride 72 elems (144 B, 16B-aligned segs).
// FINAL: dst[col*NTOK+row] = v + X2[row*CC+col] (dtype by flag)
// ---------------------------------------------------------------------------
template <int TM, bool BIAS, bool GELU, bool RES, bool OUTBF, bool FINAL>
__global__ void gemm_kernel(const bf16* __restrict__ A, const bf16* __restrict__ WT,
                            const void* __restrict__ bias, const float* __restrict__ R,
                            void* __restrict__ Cout, const float* __restrict__ X2,
                            int M, int N, int K, const int* __restrict__ dfl) {
  int f32 = *dfl;
  __shared__ __align__(16) unsigned short As[TM * 64 * 72];
  __shared__ __align__(16) unsigned short Bs[64 * 72];
  int bm = blockIdx.y * (TM * 64), bn = blockIdx.x * 64;
  int tid = threadIdx.x;
  int w = tid >> 6;
  int lane = tid & 63;
  int lm = lane & 15;
  int lk = lane >> 4;

  f32x4 acc[TM][4];
#pragma unroll
  for (int i = 0; i < TM; i++)
#pragma unroll
    for (int j = 0; j < 4; j++) acc[i][j] = (f32x4){0.f, 0.f, 0.f, 0.f};

  const unsigned short* Au = reinterpret_cast<const unsigned short*>(A);
  const unsigned short* Wu = reinterpret_cast<const unsigned short*>(WT);

  for (int k0 = 0; k0 < K; k0 += 64) {
    // A: TM*64 rows x 64 k -> TM*2 16B units/thread
#pragma unroll
    for (int u = 0; u < TM * 2; u++) {
      int unit = tid + u * 256;
      int row = unit >> 3, seg = unit & 7;
      uint4 v = *reinterpret_cast<const uint4*>(
          &Au[(size_t)(bm + row) * K + k0 + seg * 8]);
      *reinterpret_cast<uint4*>(&As[row * 72 + seg * 8]) = v;
    }
    // W^T: 64 n-rows x 64 k -> 2 16B units/thread (no transpose needed)
#pragma unroll
    for (int u = 0; u < 2; u++) {
      int unit = tid + u * 256;
      int n = unit >> 3, seg = unit & 7;
      uint4 v = *reinterpret_cast<const uint4*>(
          &Wu[(size_t)(bn + n) * K + k0 + seg * 8]);
      *reinterpret_cast<uint4*>(&Bs[n * 72 + seg * 8]) = v;
    }
    __syncthreads();

#pragma unroll
    for (int kc = 0; kc < 2; kc++) {
      bf16x8 af[TM], bfr[4];
#pragma unroll
      for (int tm = 0; tm < TM; tm++)
        af[tm] = *reinterpret_cast<const bf16x8*>(
            &As[(w * (TM * 16) + tm * 16 + lm) * 72 + kc * 32 + lk * 8]);
#pragma unroll
      for (int tn = 0; tn < 4; tn++)
        bfr[tn] = *reinterpret_cast<const bf16x8*>(
            &Bs[(tn * 16 + lm) * 72 + kc * 32 + lk * 8]);
#pragma unroll
      for (int tm = 0; tm < TM; tm++)
#pragma unroll
        for (int tn = 0; tn < 4; tn++)
          acc[tm][tn] = __builtin_amdgcn_mfma_f32_16x16x32_bf16(
              af[tm], bfr[tn], acc[tm][tn], 0, 0, 0);
    }
    __syncthreads();
  }

#pragma unroll
  for (int tn = 0; tn < 4; tn++) {
    int col = bn + tn * 16 + lm;
    float bv = BIAS ? ldin(bias, col, f32) : 0.f;
#pragma unroll
    for (int tm = 0; tm < TM; tm++) {
      int row0 = bm + w * (TM * 16) + tm * 16 + lk * 4;
#pragma unroll
      for (int r = 0; r < 4; r++) {
        int row = row0 + r;
        float v = acc[tm][tn][r];
        if (BIAS) v += bv;
        if (GELU) v = 0.5f * v * (1.0f + erff(v * 0.70710678118654752f));
        size_t idx = (size_t)row * N + col;
        if (RES) v += R[idx];
        if (FINAL) {
          float o = v + X2[(size_t)row * CC + col];
          if (f32) ((float*)Cout)[(size_t)col * NTOK + row] = o;
          else     ((bf16*)Cout)[(size_t)col * NTOK + row] = f2b(o);
        } else if (OUTBF) {
          ((bf16*)Cout)[idx] = f2b(v);
        } else {
          ((float*)Cout)[idx] = v;
        }
      }
    }
  }
}

// ---------------------------------------------------------------------------
// Time attention: one block per sequence n (1024), 192 threads
// ---------------------------------------------------------------------------
__global__ void time_attn_kernel(const bf16* __restrict__ qkv, bf16* __restrict__ O) {
  __shared__ float q[NHEAD][DD][HDIM];
  __shared__ float k[NHEAD][DD][HDIM];
  __shared__ float v[NHEAD][DD][HDIM];
  __shared__ float p[NHEAD][DD][DD];
  int n = blockIdx.x;
  int head = threadIdx.x >> 5;
  int dd = threadIdx.x & 31;
  for (int s = 0; s < DD; s++) {
    const bf16* row = qkv + (size_t)(n * DD + s) * (3 * CC);
    q[head][s][dd] = b2f(row[head * HDIM + dd]);
    k[head][s][dd] = b2f(row[CC + head * HDIM + dd]);
    v[head][s][dd] = b2f(row[2 * CC + head * HDIM + dd]);
  }
  __syncthreads();
  for (int pair = dd; pair < 64; pair += 32) {
    int sq = pair >> 3, sk = pair & 7;
    float sum = 0.f;
#pragma unroll
    for (int e = 0; e < HDIM; e++) sum += q[head][sq][e] * k[head][sk][e];
    p[head][sq][sk] = sum * ATT_SCALE;
  }
  __syncthreads();
  if (dd < DD) {
    float mx = -1e30f;
    for (int sk = 0; sk < DD; sk++) mx = fmaxf(mx, p[head][dd][sk]);
    float sum = 0.f;
    for (int sk = 0; sk < DD; sk++) { float e = expf(p[head][dd][sk] - mx); p[head][dd][sk] = e; sum += e; }
    float inv = 1.0f / sum;
    for (int sk = 0; sk < DD; sk++) p[head][dd][sk] *= inv;
  }
  __syncthreads();
  for (int sq = 0; sq < DD; sq++) {
    float sum = 0.f;
#pragma unroll
    for (int sk = 0; sk < DD; sk++) sum += p[head][sq][sk] * v[head][sk][dd];
    O[(size_t)(n * DD + sq) * CC + head * HDIM + dd] = f2b(sum);
  }
}

// ---------------------------------------------------------------------------
// Fused time epilogue + space ln1
// ---------------------------------------------------------------------------
__global__ void epi_ln1_kernel(const float* __restrict__ T, const void* __restrict__ x,
                               const void* __restrict__ gf, const void* __restrict__ bf,
                               const void* __restrict__ g1, const void* __restrict__ b1,
                               float* __restrict__ X1T, bf16* __restrict__ Y,
                               const int* __restrict__ dfl) {
  int f32 = *dfl;
  int wave = (blockIdx.x * blockDim.x + threadIdx.x) >> 6;
  int lane = threadIdx.x & 63;
  if (wave >= NTOK) return;
  const float* r = T + (size_t)wave * CC;
  float v0 = r[lane], v1 = r[lane + 64], v2 = r[lane + 128];
  float s = v0 + v1 + v2;
  for (int off = 32; off; off >>= 1) s += __shfl_xor(s, off);
  float mean = s * (1.0f / CC);
  float d0 = v0 - mean, d1 = v1 - mean, d2 = v2 - mean;
  float q = d0 * d0 + d1 * d1 + d2 * d2;
  for (int off = 32; off; off >>= 1) q += __shfl_xor(q, off);
  float rstd = rsqrtf(q * (1.0f / CC) + 1e-5f);
  int d = wave & 7, hw = wave >> 3;
  int m = d * 1024 + hw;
  float xv[3];
#pragma unroll
  for (int e = 0; e < 3; e++) {
    int c = lane + e * 64;
    float dv = (e == 0 ? d0 : (e == 1 ? d1 : d2));
    float normed = dv * rstd * ldin(gf, c, f32) + ldin(bf, c, f32);
    xv[e] = ldin(x, (size_t)((c << 3) + d) * 1024 + hw, f32) + normed;
  }
  float* o = X1T + (size_t)m * CC;
#pragma unroll
  for (int e = 0; e < 3; e++) o[lane + e * 64] = xv[e];
  float s2 = xv[0] + xv[1] + xv[2];
  for (int off = 32; off; off >>= 1) s2 += __shfl_xor(s2, off);
  float mean2 = s2 * (1.0f / CC);
  float e0 = xv[0] - mean2, e1 = xv[1] - mean2, e2 = xv[2] - mean2;
  float q2 = e0 * e0 + e1 * e1 + e2 * e2;
  for (int off = 32; off; off >>= 1) q2 += __shfl_xor(q2, off);
  float rstd2 = rsqrtf(q2 * (1.0f / CC) + 1e-5f);
  bf16* y = Y + (size_t)m * CC;
  y[lane]       = f2b(e0 * rstd2 * ldin(g1, lane, f32)       + ldin(b1, lane, f32));
  y[lane + 64]  = f2b(e1 * rstd2 * ldin(g1, lane + 64, f32)  + ldin(b1, lane + 64, f32));
  y[lane + 128] = f2b(e2 * rstd2 * ldin(g1, lane + 128, f32) + ldin(b1, lane + 128, f32));
}

// ---------------------------------------------------------------------------
// MFMA NAT attention (proven r6). Block = (frame, 8x8 tile, head), 768 blocks.
// ---------------------------------------------------------------------------
#define NKEY 224
#define PKS 40
#define PVS 232
__global__ void nat_attn_kernel(const bf16* __restrict__ qkv, const void* __restrict__ rpb,
                                bf16* __restrict__ O, const int* __restrict__ dfl) {
  int f32 = *dfl;
  __shared__ __align__(16) unsigned short Ks[NKEY * PKS];
  __shared__ __align__(16) unsigned short Vs[32 * PVS];
  __shared__ __align__(16) unsigned short Qs[64 * PKS];
  __shared__ __align__(16) unsigned short Ps[64 * PVS];
  __shared__ float rb[176];

  int blk = blockIdx.x;
  int frame = blk & 7;
  int rest = blk >> 3;
  int h = rest % 6;
  int tile = rest / 6;
  int ty = tile >> 2, tx = tile & 3;
  int base_h = min(max(ty * 8 - 3, 0), HH - 7);
  int base_w = min(max(tx * 8 - 3, 0), WW - 7);

  int tid = threadIdx.x;

  for (int i = tid; i < 169; i += 256) rb[i] = ldin(rpb, (size_t)h * 169 + i, f32);
  for (int u = tid; u < 784; u += 256) {
    int j = u >> 2, seg = u & 3;
    int a = j / 14, bb = j - a * 14;
    int ih = min(base_h + a, HH - 1), iw = min(base_w + bb, WW - 1);
    int mg = frame * 1024 + ih * 32 + iw;
    uint4 v = *reinterpret_cast<const uint4*>(qkv + (size_t)mg * 576 + 192 + h * 32 + seg * 8);
    *reinterpret_cast<uint4*>(&Ks[j * PKS + seg * 8]) = v;
  }
  for (int u = tid; u < 784; u += 256) {
    int j = u >> 2, seg = u & 3;
    int a = j / 14, bb = j - a * 14;
    int ih = min(base_h + a, HH - 1), iw = min(base_w + bb, WW - 1);
    int mg = frame * 1024 + ih * 32 + iw;
    uint4 v = *reinterpret_cast<const uint4*>(qkv + (size_t)mg * 576 + 384 + h * 32 + seg * 8);
    unsigned arr[4] = {v.x, v.y, v.z, v.w};
#pragma unroll
    for (int e = 0; e < 4; e++) {
      Vs[(seg * 8 + e * 2) * PVS + j]     = (unsigned short)(arr[e] & 0xffffu);
      Vs[(seg * 8 + e * 2 + 1) * PVS + j] = (unsigned short)(arr[e] >> 16);
    }
  }
  for (int u = tid; u < 32 * (PVS - 196); u += 256) {
    int dd = u / (PVS - 196), c = 196 + u % (PVS - 196);
    Vs[dd * PVS + c] = 0;
  }
  {
    int q = tid >> 2, seg = tid & 3;
    int qy = ty * 8 + (q >> 3), qx = tx * 8 + (q & 7);
    int mg = frame * 1024 + qy * 32 + qx;
    uint4 v = *reinterpret_cast<const uint4*>(qkv + (size_t)mg * 576 + h * 32 + seg * 8);
    *reinterpret_cast<uint4*>(&Qs[q * PKS + seg * 8]) = v;
  }
  __syncthreads();

  int w = tid >> 6;
  int lane = tid & 63;
  int c = lane & 15;
  int lk = lane >> 4;

  bf16x8 aq = *reinterpret_cast<const bf16x8*>(&Qs[(w * 16 + c) * PKS + lk * 8]);
  f32x4 sc[14];
#pragma unroll
  for (int f = 0; f < 14; f++) {
    bf16x8 bk = *reinterpret_cast<const bf16x8*>(&Ks[(f * 16 + c) * PKS + lk * 8]);
    sc[f] = __builtin_amdgcn_mfma_f32_16x16x32_bf16(aq, bk, (f32x4){0.f, 0.f, 0.f, 0.f}, 0, 0, 0);
  }

#pragma unroll
  for (int f = 0; f < 14; f++) {
    int key = f * 16 + c;
    int a = key / 14, bb = key - a * 14;
    int ih = base_h + a, iw = base_w + bb;
    bool keyok = key < 196;
#pragma unroll
    for (int r = 0; r < 4; r++) {
      int qloc = w * 16 + lk * 4 + r;
      int qy = ty * 8 + (qloc >> 3), qx = tx * 8 + (qloc & 7);
      int sh = min(max(qy - 3, 0), HH - 7);
      int sw = min(max(qx - 3, 0), WW - 7);
      bool valid = keyok && ((unsigned)(ih - sh) < 7u) && ((unsigned)(iw - sw) < 7u);
      int bidx = valid ? (ih - qy + 6) * 13 + (iw - qx + 6) : 0;
      float s = sc[f][r] * ATT_SCALE + rb[bidx];
      sc[f][r] = valid ? s : -1e30f;
    }
  }

  float sm[4];
#pragma unroll
  for (int r = 0; r < 4; r++) {
    float m = sc[0][r];
#pragma unroll
    for (int f = 1; f < 14; f++) m = fmaxf(m, sc[f][r]);
    for (int off = 8; off; off >>= 1) m = fmaxf(m, __shfl_xor(m, off));
    float s = 0.f;
#pragma unroll
    for (int f = 0; f < 14; f++) { float e = __expf(sc[f][r] - m); sc[f][r] = e; s += e; }
    for (int off = 8; off; off >>= 1) s += __shfl_xor(s, off);
    sm[r] = 1.0f / s;
  }
#pragma unroll
  for (int f = 0; f < 14; f++)
#pragma unroll
    for (int r = 0; r < 4; r++)
      Ps[(w * 16 + lk * 4 + r) * PVS + f * 16 + c] = f2us(sc[f][r] * sm[r]);
  __syncthreads();

  f32x4 oacc[2] = {(f32x4){0.f, 0.f, 0.f, 0.f}, (f32x4){0.f, 0.f, 0.f, 0.f}};
#pragma unroll
  for (int kt = 0; kt < 7; kt++) {
    bf16x8 ap = *reinterpret_cast<const bf16x8*>(&Ps[(w * 16 + c) * PVS + kt * 32 + lk * 8]);
#pragma unroll
    for (int dt = 0; dt < 2; dt++) {
      bf16x8 bv = *reinterpret_cast<const bf16x8*>(&Vs[(dt * 16 + c) * PVS + kt * 32 + lk * 8]);
      oacc[dt] = __builtin_amdgcn_mfma_f32_16x16x32_bf16(ap, bv, oacc[dt], 0, 0, 0);
    }
  }

#pragma unroll
  for (int dt = 0; dt < 2; dt++)
#pragma unroll
    for (int r = 0; r < 4; r++) {
      int qloc = w * 16 + lk * 4 + r;
      int qy = ty * 8 + (qloc >> 3), qx = tx * 8 + (qloc & 7);
      int mg = frame * 1024 + qy * 32 + qx;
      O[(size_t)mg * CC + h * 32 + dt * 16 + c] = f2b(oacc[dt][r]);
    }
}

// ---------------------------------------------------------------------------
extern "C" void kernel_launch(void* const* d_in, const int* in_sizes, int n_in,
                              void* d_out, int out_size, void* d_ws, size_t ws_size,
                              hipStream_t stream) {
  const void* x        = d_in[0];
  const void* pos_emb  = d_in[1];
  const void* t_ln1_g  = d_in[2];
  const void* t_ln1_b  = d_in[3];
  const void* t_qkv_w  = d_in[4];
  const void* t_out_w  = d_in[5];
  const void* t_out_b  = d_in[6];
  const void* t_ln2_g  = d_in[7];
  const void* t_ln2_b  = d_in[8];
  const void* t_fc1_w  = d_in[9];
  const void* t_fc1_b  = d_in[10];
  const void* t_fc2_w  = d_in[11];
  const void* t_fc2_b  = d_in[12];
  const void* t_lnf_g  = d_in[13];
  const void* t_lnf_b  = d_in[14];
  const void* s_ln1_g  = d_in[15];
  const void* s_ln1_b  = d_in[16];
  const void* s_qkv_w  = d_in[17];
  const void* s_qkv_b  = d_in[18];
  const void* s_rpb    = d_in[19];
  const void* s_proj_w = d_in[20];
  const void* s_proj_b = d_in[21];
  const void* s_ln2_g  = d_in[22];
  const void* s_ln2_b  = d_in[23];
  const void* s_fc1_w  = d_in[24];
  const void* s_fc1_b  = d_in[25];
  const void* s_fc2_w  = d_in[26];
  const void* s_fc2_b  = d_in[27];

  // Workspace: [0,SZ) f32 T/S | [SZ,2SZ) f32 X1T | [2SZ,2.5SZ) bf16 Y |
  // [2.5SZ,3SZ) bf16 O | [3SZ,5SZ) bf16 QKV/Hb | [5SZ] int dfl |
  // [5SZ+4, +442368 f32) bf16 WT (884736 elems). Total ~33.3 MB.
  float* ws = (float*)d_ws;
  const size_t SZ = (size_t)NTOK * CC;
  const size_t need = (5 * SZ + 4 + 442368 + 16) * sizeof(float);
  if (ws_size < need) return;

  float* T   = ws;
  float* X1T = ws + SZ;
  bf16*  Y   = (bf16*)(ws + 2 * SZ);
  bf16*  O   = (bf16*)(ws + 2 * SZ + SZ / 2);
  bf16*  QKV = (bf16*)(ws + 3 * SZ);
  bf16*  Hb  = QKV;
  float* S   = T;
  int*   dfl = (int*)(ws + 5 * SZ);
  bf16*  WT  = (bf16*)(ws + 5 * SZ + 4);

  dim3 blk256(256);

  probe_dtype_kernel<<<1, 64, 0, stream>>>((const unsigned short*)x, dfl);
  wconv_kernel<<<3456, blk256, 0, stream>>>(
      t_qkv_w, t_out_w, t_fc1_w, t_fc2_w, s_qkv_w, s_proj_w, s_fc1_w, s_fc2_w, WT, dfl);

  // ---- Time transformer ----
  build_ln1_kernel<<<NTOK / 4, blk256, 0, stream>>>(x, pos_emb, t_ln1_g, t_ln1_b, T, Y, dfl);
  gemm_kernel<2, false, false, false, true, false><<<dim3(9, 64), blk256, 0, stream>>>(
      Y, WT + WOFF_TQKV, nullptr, nullptr, QKV, nullptr, NTOK, 3 * CC, CC, dfl);
  time_attn_kernel<<<1024, 192, 0, stream>>>(QKV, O);
  gemm_kernel<1, true, false, true, false, false><<<dim3(3, 128), blk256, 0, stream>>>(
      O, WT + WOFF_TOUT, t_out_b, T, T, nullptr, NTOK, CC, CC, dfl);
  ln_kernel<<<NTOK / 4, blk256, 0, stream>>>(T, Y, t_ln2_g, t_ln2_b, NTOK, dfl);
  gemm_kernel<2, true, true, false, true, false><<<dim3(12, 64), blk256, 0, stream>>>(
      Y, WT + WOFF_TFC1, t_fc1_b, nullptr, Hb, nullptr, NTOK, HID, CC, dfl);
  gemm_kernel<1, true, false, true, false, false><<<dim3(3, 128), blk256, 0, stream>>>(
      Hb, WT + WOFF_TFC2, t_fc2_b, T, T, nullptr, NTOK, CC, HID, dfl);
  epi_ln1_kernel<<<NTOK / 4, blk256, 0, stream>>>(
      T, x, t_lnf_g, t_lnf_b, s_ln1_g, s_ln1_b, X1T, Y, dfl);

  // ---- Space transformer ----
  gemm_kernel<2, true, false, false, true, false><<<dim3(9, 64), blk256, 0, stream>>>(
      Y, WT + WOFF_SQKV, s_qkv_b, nullptr, QKV, nullptr, NTOK, 3 * CC, CC, dfl);
  nat_attn_kernel<<<768, blk256, 0, stream>>>(QKV, s_rpb, O, dfl);
  gemm_kernel<1, true, false, true, false, false><<<dim3(3, 128), blk256, 0, stream>>>(
      O, WT + WOFF_SPROJ, s_proj_b, X1T, S, nullptr, NTOK, CC, CC, dfl);
  ln_kernel<<<NTOK / 4, blk256, 0, stream>>>(S, Y, s_ln2_g, s_ln2_b, NTOK, dfl);
  gemm_kernel<2, true, true, false, true, false><<<dim3(12, 64), blk256, 0, stream>>>(
      Y, WT + WOFF_SFC1, s_fc1_b, nullptr, Hb, nullptr, NTOK, HID, CC, dfl);
  gemm_kernel<1, true, false, true, false, true><<<dim3(3, 128), blk256, 0, stream>>>(
      Hb, WT + WOFF_SFC2, s_fc2_b, S, d_out, X1T, NTOK, CC, HID, dfl);
}